// Round 11
// baseline (393.610 us; speedup 1.0000x reference)
//
#include <hip/hip_runtime.h>
#include <math.h>

#define N_NODES 10000
#define N_EDGES 160000
#define N_FEAT  512
#define HEADS   8
#define HID     128

typedef __attribute__((ext_vector_type(8))) short bf16x8;
typedef __attribute__((ext_vector_type(4))) float f32x4;

// ---------------------------------------------------------------------------
// fp32 <-> bf16 helpers
// ---------------------------------------------------------------------------
__device__ inline unsigned short f2bf_rne(float f) {
  unsigned int u = __float_as_uint(f);
  unsigned int r = u + 0x7fffu + ((u >> 16) & 1u);
  return (unsigned short)(r >> 16);
}
__device__ inline float bf2f(unsigned int b) {
  return __uint_as_float(b << 16);
}

// ---------------------------------------------------------------------------
// Split fp32 [R][K] into hi/lo bf16 in MFMA-fragment-major layout:
// unit (rb,kq,r) at index (rb*K8+kq)*16+r holds 8 bf16 = A[rb*16+r][kq*8..+8].
// ---------------------------------------------------------------------------
__global__ __launch_bounds__(256)
void split_frag(const float* __restrict__ in, unsigned short* __restrict__ hi,
                unsigned short* __restrict__ lo, int R, int K8, int total) {
  int idx = blockIdx.x * 256 + threadIdx.x;
  if (idx >= total) return;
  int r = idx & 15;
  int t = idx >> 4;
  int kq = t % K8;
  int rb = t / K8;
  int row = rb * 16 + r;
  float v[8] = {0.f, 0.f, 0.f, 0.f, 0.f, 0.f, 0.f, 0.f};
  if (row < R) {
    const float* p = in + (size_t)row * (K8 * 8) + kq * 8;
    float4 a = *(const float4*)p;
    float4 b = *(const float4*)(p + 4);
    v[0] = a.x; v[1] = a.y; v[2] = a.z; v[3] = a.w;
    v[4] = b.x; v[5] = b.y; v[6] = b.z; v[7] = b.w;
  }
  union { unsigned short u[8]; int4 v4; } H, L;
  #pragma unroll
  for (int e = 0; e < 8; ++e) {
    unsigned short hb_ = f2bf_rne(v[e]);
    H.u[e] = hb_;
    L.u[e] = f2bf_rne(v[e] - bf2f(hb_));
  }
  *(int4*)&hi[(size_t)idx * 8] = H.v4;
  *(int4*)&lo[(size_t)idx * 8] = L.v4;
}

// ---------------------------------------------------------------------------
// LDS-free split-bf16 MFMA GEMM, SINGLE-WAVE blocks for occupancy:
// each 64-thread block computes a 64x32 tile (acc[4][2]); grid =
// 20 mt8 x 4 nq x 8 head x 8 rr = 5120 waves (~20/CU). blk%8 == mtile%8
// keeps all 32 blocks of an m-tile on one XCD (L2 A-reuse); B is L2-resident.
// Scores epilogue: partial col-sums atomicAdd'ed into pre-zeroed si/sj.
// ---------------------------------------------------------------------------
__global__ __launch_bounds__(64, 4)
void gemm_frag(const unsigned short* __restrict__ Afh,
               const unsigned short* __restrict__ Afl,
               const unsigned short* __restrict__ Bfh,
               const unsigned short* __restrict__ Bfl,
               const float* __restrict__ avec,
               unsigned short* __restrict__ hb,
               float* __restrict__ si, float* __restrict__ sj,
               int M, int K) {
  int lane = threadIdx.x;
  int r = lane & 15, q = lane >> 4;

  int blk = blockIdx.x;
  int rr = blk & 7;
  int t = blk >> 3;
  int head = t & 7; t >>= 3;
  int nq = t & 3;
  int mt8 = t >> 2;
  int mtile = mt8 * 8 + rr;        // blk%8 == mtile%8 -> XCD affinity
  int m0 = mtile * 64;
  int wn = nq * 32;
  int K8 = K >> 3;

  const bf16x8* pAh = (const bf16x8*)Afh;
  const bf16x8* pAl = (const bf16x8*)Afl;
  const bf16x8* pBh = (const bf16x8*)Bfh;
  const bf16x8* pBl = (const bf16x8*)Bfl;
  size_t rstep = (size_t)K8 * 16;
  size_t aidx = (size_t)(m0 >> 4) * rstep + (size_t)q * 16 + r;
  size_t bidx = (size_t)(head * 8 + (wn >> 4)) * rstep + (size_t)q * 16 + r;

  f32x4 acc[4][2] = {};

  for (int k0 = 0; k0 < K; k0 += 32, aidx += 64, bidx += 64) {
    bf16x8 ah[4], al[4], bh[2], bl[2];
    #pragma unroll
    for (int i = 0; i < 4; ++i) {
      ah[i] = pAh[aidx + i * rstep];
      al[i] = pAl[aidx + i * rstep];
    }
    #pragma unroll
    for (int j = 0; j < 2; ++j) {
      bh[j] = pBh[bidx + j * rstep];
      bl[j] = pBl[bidx + j * rstep];
    }
    #pragma unroll
    for (int i = 0; i < 4; ++i)
      #pragma unroll
      for (int j = 0; j < 2; ++j) {
        acc[i][j] = __builtin_amdgcn_mfma_f32_16x16x32_bf16(ah[i], bh[j], acc[i][j], 0, 0, 0);
        acc[i][j] = __builtin_amdgcn_mfma_f32_16x16x32_bf16(ah[i], bl[j], acc[i][j], 0, 0, 0);
        acc[i][j] = __builtin_amdgcn_mfma_f32_16x16x32_bf16(al[i], bh[j], acc[i][j], 0, 0, 0);
      }
  }

  // --- epilogue: C/D layout col = r, row = q*4 + reg (per 16x16 frag) ---
  const float* av = avec + (size_t)head * (2 * HID);
  float aiv[2], ajv[2];
  #pragma unroll
  for (int j = 0; j < 2; ++j) {
    int c = wn + j * 16 + r;
    aiv[j] = av[c];
    ajv[j] = av[HID + c];
  }
  #pragma unroll
  for (int i = 0; i < 4; ++i) {
    #pragma unroll
    for (int reg = 0; reg < 4; ++reg) {
      int row = m0 + i * 16 + q * 4 + reg;
      float vsi = 0.f, vsj = 0.f;
      #pragma unroll
      for (int j = 0; j < 2; ++j) {
        float v = acc[i][j][reg];
        vsi = fmaf(v, aiv[j], vsi);
        vsj = fmaf(v, ajv[j], vsj);
        if (row < M)
          hb[((size_t)head * M + row) * HID + wn + j * 16 + r] = f2bf_rne(v);
      }
      #pragma unroll
      for (int o = 8; o >= 1; o >>= 1) {
        vsi += __shfl_xor(vsi, o);
        vsj += __shfl_xor(vsj, o);
      }
      if (r == 0 && row < M) {
        atomicAdd(&si[(size_t)row * HEADS + head], vsi);
        atomicAdd(&sj[(size_t)row * HEADS + head], vsj);
      }
    }
  }
}

// ---------------------------------------------------------------------------
// CSR build
// ---------------------------------------------------------------------------
__global__ void count_kernel(const int* __restrict__ dst, int* __restrict__ deg, int E) {
  int e = blockIdx.x * blockDim.x + threadIdx.x;
  if (e < E) atomicAdd(&deg[dst[e]], 1);
}

__global__ __launch_bounds__(1024)
void scan_kernel(const int* __restrict__ deg, int* __restrict__ off, int N) {
  __shared__ int sums[1024];
  const int PER = 10;
  int tid = threadIdx.x;
  int base = tid * PER;
  int loc[PER];
  int run = 0;
  #pragma unroll
  for (int j = 0; j < PER; ++j) {
    int v = (base + j < N) ? deg[base + j] : 0;
    run += v;
    loc[j] = run;
  }
  sums[tid] = run;
  __syncthreads();
  for (int o = 1; o < 1024; o <<= 1) {
    int v = (tid >= o) ? sums[tid - o] : 0;
    __syncthreads();
    sums[tid] += v;
    __syncthreads();
  }
  int ex = sums[tid] - run;
  if (tid == 0) off[0] = 0;
  #pragma unroll
  for (int j = 0; j < PER; ++j)
    if (base + j < N) off[base + j + 1] = ex + loc[j];
}

__global__ void fill_kernel(const int* __restrict__ src, const int* __restrict__ dst,
                            const int* __restrict__ off, int* __restrict__ cursor,
                            int* __restrict__ ssrc, int E) {
  int e = blockIdx.x * blockDim.x + threadIdx.x;
  if (e < E) {
    int d = dst[e];
    int p = atomicAdd(&cursor[d], 1);
    ssrc[off[d] + p] = src[e];
  }
}

// ---------------------------------------------------------------------------
// Edge softmax weights: one wave per dst node, lane = eidx*8 + head.
// ---------------------------------------------------------------------------
__global__ __launch_bounds__(256)
void alpha_kernel(const float* __restrict__ si, const float* __restrict__ sj,
                  const int* __restrict__ off, const int* __restrict__ ssrc,
                  float* __restrict__ w, float* __restrict__ invden, int N) {
  int wv = (blockIdx.x * blockDim.x + threadIdx.x) >> 6;
  if (wv >= N) return;
  int lane = threadIdx.x & 63;
  int eidx = lane >> 3, head = lane & 7;
  int begin = off[wv], end = off[wv + 1];
  float s_i = si[wv * HEADS + head];

  float m = -INFINITY;
  for (int k0 = begin; k0 < end; k0 += 8) {
    int k = k0 + eidx;
    if (k < end) {
      float e = s_i + sj[ssrc[k] * HEADS + head];
      e = e > 0.f ? e : 0.01f * e;
      m = fmaxf(m, e);
    }
  }
  m = fmaxf(m, __shfl_xor(m, 8));
  m = fmaxf(m, __shfl_xor(m, 16));
  m = fmaxf(m, __shfl_xor(m, 32));

  float sum = 0.f;
  for (int k0 = begin; k0 < end; k0 += 8) {
    int k = k0 + eidx;
    if (k < end) {
      float e = s_i + sj[ssrc[k] * HEADS + head];
      e = e > 0.f ? e : 0.01f * e;
      float wt = expf(e - m);
      w[(size_t)k * HEADS + head] = wt;
      sum += wt;
    }
  }
  sum += __shfl_xor(sum, 8);
  sum += __shfl_xor(sum, 16);
  sum += __shfl_xor(sum, 32);
  if (eidx == 0)
    invden[wv * HEADS + head] = sum > 0.f ? 1.0f / sum : 0.f;
}

// ---------------------------------------------------------------------------
// Aggregation: one wave per (dst, head); head = blockIdx.x & 7 (XCD/L2
// affinity). Wave = 4 groups x 16 lanes; 16 edge-vectors in flight.
// Output aggbuf is bf16 (halves the HBM round-trip).
// ---------------------------------------------------------------------------
__global__ __launch_bounds__(512)
void gat_aggregate3(const unsigned short* __restrict__ hb,
                    const float* __restrict__ w, const float* __restrict__ invden,
                    const int* __restrict__ off, const int* __restrict__ ssrc,
                    unsigned short* __restrict__ aggb, int N) {
  int head = blockIdx.x & 7;
  int n = (blockIdx.x >> 3) * 8 + (threadIdx.x >> 6);
  if (n >= N) return;
  int lane = threadIdx.x & 63;
  int grp = lane >> 4;
  int l = lane & 15;
  const unsigned short* hbase = hb + (size_t)head * N * HID;
  int begin = off[n], end = off[n + 1];

  float a0 = 0.f, a1 = 0.f, a2 = 0.f, a3 = 0.f;
  float a4 = 0.f, a5 = 0.f, a6 = 0.f, a7 = 0.f;

  for (int k0 = begin; k0 < end; k0 += 16) {
    int kk[4];
    float wv[4];
    int sv[4];
    #pragma unroll
    for (int u = 0; u < 4; ++u) {
      int k = k0 + u * 4 + grp;
      kk[u] = k < end ? k : begin;
      sv[u] = ssrc[kk[u]];
      wv[u] = w[(size_t)kk[u] * HEADS + head];
      if (k >= end) wv[u] = 0.f;
    }
    int4 pv[4];
    #pragma unroll
    for (int u = 0; u < 4; ++u)
      pv[u] = *(const int4*)&hbase[(size_t)sv[u] * HID + l * 8];
    #pragma unroll
    for (int u = 0; u < 4; ++u) {
      float wu = wv[u];
      int4 p = pv[u];
      a0 = fmaf(wu, bf2f((unsigned)p.x & 0xffffu), a0);
      a1 = fmaf(wu, __uint_as_float((unsigned)p.x & 0xffff0000u), a1);
      a2 = fmaf(wu, bf2f((unsigned)p.y & 0xffffu), a2);
      a3 = fmaf(wu, __uint_as_float((unsigned)p.y & 0xffff0000u), a3);
      a4 = fmaf(wu, bf2f((unsigned)p.z & 0xffffu), a4);
      a5 = fmaf(wu, __uint_as_float((unsigned)p.z & 0xffff0000u), a5);
      a6 = fmaf(wu, bf2f((unsigned)p.w & 0xffffu), a6);
      a7 = fmaf(wu, __uint_as_float((unsigned)p.w & 0xffff0000u), a7);
    }
  }
  a0 += __shfl_xor(a0, 16); a1 += __shfl_xor(a1, 16);
  a2 += __shfl_xor(a2, 16); a3 += __shfl_xor(a3, 16);
  a4 += __shfl_xor(a4, 16); a5 += __shfl_xor(a5, 16);
  a6 += __shfl_xor(a6, 16); a7 += __shfl_xor(a7, 16);
  a0 += __shfl_xor(a0, 32); a1 += __shfl_xor(a1, 32);
  a2 += __shfl_xor(a2, 32); a3 += __shfl_xor(a3, 32);
  a4 += __shfl_xor(a4, 32); a5 += __shfl_xor(a5, 32);
  a6 += __shfl_xor(a6, 32); a7 += __shfl_xor(a7, 32);

  if (grp == 0) {
    float inv = invden[n * HEADS + head];
    union { unsigned short u[8]; int4 v4; } P;
    P.u[0] = f2bf_rne(a0 * inv); P.u[1] = f2bf_rne(a1 * inv);
    P.u[2] = f2bf_rne(a2 * inv); P.u[3] = f2bf_rne(a3 * inv);
    P.u[4] = f2bf_rne(a4 * inv); P.u[5] = f2bf_rne(a5 * inv);
    P.u[6] = f2bf_rne(a6 * inv); P.u[7] = f2bf_rne(a7 * inv);
    *(int4*)&aggb[((size_t)head * N + n) * HID + l * 8] = P.v4;
  }
}

// ---------------------------------------------------------------------------
// Head mean + ELU (bf16 aggbuf), writing layer-2 A in frag-major split form
// ---------------------------------------------------------------------------
__global__ __launch_bounds__(256)
void headmean_frag(const unsigned short* __restrict__ aggb,
                   unsigned short* __restrict__ hi, unsigned short* __restrict__ lo,
                   int N) {
  int idx = blockIdx.x * 256 + threadIdx.x;   // (rb,kq,r), K8=16
  int total = ((N + 15) / 16) * 256;
  if (idx >= total) return;
  int r = idx & 15;
  int kq = (idx >> 4) & 15;
  int rb = idx >> 8;
  int n = rb * 16 + r;
  float s[8] = {0.f, 0.f, 0.f, 0.f, 0.f, 0.f, 0.f, 0.f};
  if (n < N) {
    #pragma unroll
    for (int hh = 0; hh < HEADS; ++hh) {
      int4 pv = *(const int4*)&aggb[((size_t)hh * N + n) * HID + kq * 8];
      s[0] += bf2f((unsigned)pv.x & 0xffffu);
      s[1] += __uint_as_float((unsigned)pv.x & 0xffff0000u);
      s[2] += bf2f((unsigned)pv.y & 0xffffu);
      s[3] += __uint_as_float((unsigned)pv.y & 0xffff0000u);
      s[4] += bf2f((unsigned)pv.z & 0xffffu);
      s[5] += __uint_as_float((unsigned)pv.z & 0xffff0000u);
      s[6] += bf2f((unsigned)pv.w & 0xffffu);
      s[7] += __uint_as_float((unsigned)pv.w & 0xffff0000u);
    }
  }
  union { unsigned short u[8]; int4 v4; } H, L;
  #pragma unroll
  for (int e = 0; e < 8; ++e) {
    float v = s[e] * (1.0f / HEADS);
    v = v > 0.f ? v : (expf(v) - 1.0f);   // ELU
    unsigned short hb_ = f2bf_rne(v);
    H.u[e] = hb_;
    L.u[e] = f2bf_rne(v - bf2f(hb_));
  }
  *(int4*)&hi[(size_t)idx * 8] = H.v4;
  *(int4*)&lo[(size_t)idx * 8] = L.v4;
}

// ---------------------------------------------------------------------------
// Layer-2 tail: head mean + ELU + graph pooling fused (no emb2 materialized).
// Block = 16 nodes x 16 dim-groups; LDS reduce over nodes; atomicAdd to g.
// ---------------------------------------------------------------------------
__global__ __launch_bounds__(256)
void headmean_pool(const unsigned short* __restrict__ aggb, float* __restrict__ g,
                   int N) {
  __shared__ float sm[16][128];
  int t = threadIdx.x;
  int nl = t >> 4, dg = t & 15;
  int n = blockIdx.x * 16 + nl;
  float v[8] = {0.f, 0.f, 0.f, 0.f, 0.f, 0.f, 0.f, 0.f};
  if (n < N) {
    #pragma unroll
    for (int hh = 0; hh < HEADS; ++hh) {
      int4 pv = *(const int4*)&aggb[((size_t)hh * N + n) * HID + dg * 8];
      v[0] += bf2f((unsigned)pv.x & 0xffffu);
      v[1] += __uint_as_float((unsigned)pv.x & 0xffff0000u);
      v[2] += bf2f((unsigned)pv.y & 0xffffu);
      v[3] += __uint_as_float((unsigned)pv.y & 0xffff0000u);
      v[4] += bf2f((unsigned)pv.z & 0xffffu);
      v[5] += __uint_as_float((unsigned)pv.z & 0xffff0000u);
      v[6] += bf2f((unsigned)pv.w & 0xffffu);
      v[7] += __uint_as_float((unsigned)pv.w & 0xffff0000u);
    }
    #pragma unroll
    for (int e = 0; e < 8; ++e) {
      float x = v[e] * (1.0f / HEADS);
      v[e] = x > 0.f ? x : (expf(x) - 1.0f);   // ELU
    }
  }
  #pragma unroll
  for (int e = 0; e < 8; ++e) sm[nl][dg * 8 + e] = v[e];
  __syncthreads();
  if (t < 128) {
    float s = 0.f;
    #pragma unroll
    for (int nn = 0; nn < 16; ++nn) s += sm[nn][t];
    atomicAdd(&g[t], s);
  }
}

// ---------------------------------------------------------------------------
// LayerNorm + MLP head
// ---------------------------------------------------------------------------
__global__ __launch_bounds__(128)
void mlp_kernel(const float* __restrict__ g, const float* __restrict__ ln_g,
                const float* __restrict__ ln_b, const float* __restrict__ Wl1,
                const float* __restrict__ bl1, const float* __restrict__ Wl2,
                const float* __restrict__ bl2, const float* __restrict__ Wl3,
                const float* __restrict__ bl3, float* __restrict__ out, float invN) {
  __shared__ float red[128];
  __shared__ float gn[128];
  __shared__ float x1[64];
  __shared__ float x2[16];
  int t = threadIdx.x;
  float gg = g[t] * invN;
  red[t] = gg;
  __syncthreads();
  for (int o = 64; o > 0; o >>= 1) {
    if (t < o) red[t] += red[t + o];
    __syncthreads();
  }
  float mu = red[0] * (1.0f / HID);
  __syncthreads();
  float dv = gg - mu;
  red[t] = dv * dv;
  __syncthreads();
  for (int o = 64; o > 0; o >>= 1) {
    if (t < o) red[t] += red[t + o];
    __syncthreads();
  }
  float var = red[0] * (1.0f / HID);
  gn[t] = dv / sqrtf(var + 1e-5f) * ln_g[t] + ln_b[t];
  __syncthreads();
  if (t < 64) {
    float s = bl1[t];
    for (int k = 0; k < 128; ++k) s += Wl1[t * 128 + k] * gn[k];
    x1[t] = s > 0.f ? s : 0.01f * s;
  }
  __syncthreads();
  if (t < 16) {
    float s = bl2[t];
    for (int k = 0; k < 64; ++k) s += Wl2[t * 64 + k] * x1[k];
    x2[t] = s > 0.f ? s : 0.01f * s;
  }
  __syncthreads();
  if (t < 16) {
    float s = bl3[t];
    for (int k = 0; k < 16; ++k) s += Wl3[t * 16 + k] * x2[k];
    out[t] = s > 0.f ? s : 0.f;
  }
}

// ---------------------------------------------------------------------------
extern "C" void kernel_launch(void* const* d_in, const int* in_sizes, int n_in,
                              void* d_out, int out_size, void* d_ws, size_t ws_size,
                              hipStream_t stream) {
  const float* x    = (const float*)d_in[0];
  const int*   esrc = (const int*)d_in[1];
  const int*   edst = (const int*)d_in[2];
  const float* W1   = (const float*)d_in[3];
  const float* a1   = (const float*)d_in[4];
  const float* W2   = (const float*)d_in[5];
  const float* a2   = (const float*)d_in[6];
  const float* ln_g = (const float*)d_in[7];
  const float* ln_b = (const float*)d_in[8];
  const float* Wl1  = (const float*)d_in[9];
  const float* bl1  = (const float*)d_in[10];
  const float* Wl2  = (const float*)d_in[11];
  const float* bl2  = (const float*)d_in[12];
  const float* Wl3  = (const float*)d_in[13];
  const float* bl3  = (const float*)d_in[14];
  float* out = (float*)d_out;

  const int RBPAD = 640;  // row-blocks padded (10240 rows) for in-bounds frags

  // workspace carve-up (16B-aligned sections)
  unsigned short* aggb = (unsigned short*)d_ws;               // 10,240,000 us (20.5 MB)
  float* si   = (float*)(aggb + (size_t)N_NODES * HEADS * HID); // 80,000
  float* sj   = si + N_NODES * HEADS;                         // 80,000 (adjacent to si)
  float* g    = sj + N_NODES * HEADS;                         // 128 (adjacent to sj)
  float* wbuf = g + 128;                                      // 1,280,000
  float* invd = wbuf + (size_t)N_EDGES * HEADS;               // 80,000
  int*   deg  = (int*)(invd + N_NODES * HEADS);               // 10,000
  int*   cur  = deg + N_NODES;                                // 10,000 (adjacent)
  int*   off  = cur + N_NODES;                                // 10,001 -> pad to 10,004
  int*   ssrc = off + 10004;                                  // 160,000
  unsigned short* Afh = (unsigned short*)(ssrc + N_EDGES);    // 640*64*128 us
  unsigned short* Afl = Afh + (size_t)RBPAD * 64 * 128;
  unsigned short* Bfh = Afl + (size_t)RBPAD * 64 * 128;
  unsigned short* Bfl = Bfh + (size_t)64 * 64 * 128;
  unsigned short* hb  = Bfl + (size_t)64 * 64 * 128;          // 20.5 MB

  // CSR by dst (deg+cursor zeroed in ONE memset)
  hipMemsetAsync(deg, 0, 2 * N_NODES * sizeof(int), stream);
  count_kernel<<<(N_EDGES + 255) / 256, 256, 0, stream>>>(edst, deg, N_EDGES);
  scan_kernel<<<1, 1024, 0, stream>>>(deg, off, N_NODES);
  fill_kernel<<<(N_EDGES + 255) / 256, 256, 0, stream>>>(esrc, edst, off, cur, ssrc, N_EDGES);

  // zero si+sj+g in one memset (adjacent)
  hipMemsetAsync(si, 0, (2 * N_NODES * HEADS + 128) * sizeof(float), stream);

  int gemmGrid = 20 * 4 * 8 * 8;              // 5120 single-wave blocks
  int aggGrid = (N_NODES / 8) * 8;

  // ---- Layer 1 ----
  {
    int totalA = RBPAD * 64 * 16;             // 16B units, K8=64
    split_frag<<<(totalA + 255) / 256, 256, 0, stream>>>(x, Afh, Afl, N_NODES, 64, totalA);
    int totalB = 64 * 64 * 16;                // 1024 rows, K8=64
    split_frag<<<(totalB + 255) / 256, 256, 0, stream>>>(W1, Bfh, Bfl, HEADS * HID, 64, totalB);
    gemm_frag<<<gemmGrid, 64, 0, stream>>>(Afh, Afl, Bfh, Bfl, a1, hb,
                                           si, sj, N_NODES, N_FEAT);
  }
  alpha_kernel<<<(N_NODES + 3) / 4, 256, 0, stream>>>(si, sj, off, ssrc, wbuf, invd, N_NODES);
  gat_aggregate3<<<aggGrid, 512, 0, stream>>>(hb, wbuf, invd, off, ssrc, aggb, N_NODES);
  {
    int totalHM = ((N_NODES + 15) / 16) * 256;
    headmean_frag<<<(totalHM + 255) / 256, 256, 0, stream>>>(aggb, Afh, Afl, N_NODES);
  }

  // zero si+sj for layer 2 (g keeps accumulating only after layer-2 agg)
  hipMemsetAsync(si, 0, 2 * N_NODES * HEADS * sizeof(float), stream);

  // ---- Layer 2 ----
  {
    int totalB = 64 * 16 * 16;                // 1024 rows, K8=16
    split_frag<<<(totalB + 255) / 256, 256, 0, stream>>>(W2, Bfh, Bfl, HEADS * HID, 16, totalB);
    gemm_frag<<<gemmGrid, 64, 0, stream>>>(Afh, Afl, Bfh, Bfl, a2, hb,
                                           si, sj, N_NODES, HID);
  }
  alpha_kernel<<<(N_NODES + 3) / 4, 256, 0, stream>>>(si, sj, off, ssrc, wbuf, invd, N_NODES);
  gat_aggregate3<<<aggGrid, 512, 0, stream>>>(hb, wbuf, invd, off, ssrc, aggb, N_NODES);

  // ---- fused head-mean + pooling + MLP head ----
  headmean_pool<<<(N_NODES + 15) / 16, 256, 0, stream>>>(aggb, g, N_NODES);
  mlp_kernel<<<1, 128, 0, stream>>>(g, ln_g, ln_b, Wl1, bl1, Wl2, bl2, Wl3, bl3,
                                    out, 1.0f / N_NODES);
}

// Round 12
// 317.867 us; speedup vs baseline: 1.2383x; 1.2383x over previous
//
#include <hip/hip_runtime.h>
#include <math.h>

#define N_NODES 10000
#define N_EDGES 160000
#define N_FEAT  512
#define HEADS   8
#define HID     128

typedef __attribute__((ext_vector_type(8))) short bf16x8;
typedef __attribute__((ext_vector_type(4))) float f32x4;

// ---------------------------------------------------------------------------
// fp32 <-> bf16 helpers
// ---------------------------------------------------------------------------
__device__ inline unsigned short f2bf_rne(float f) {
  unsigned int u = __float_as_uint(f);
  unsigned int r = u + 0x7fffu + ((u >> 16) & 1u);
  return (unsigned short)(r >> 16);
}
__device__ inline float bf2f(unsigned int b) {
  return __uint_as_float(b << 16);
}

// ---------------------------------------------------------------------------
// Split fp32 [R][K] into hi/lo bf16 in MFMA-fragment-major layout:
// unit (rb,kq,r) at index (rb*K8+kq)*16+r holds 8 bf16 = A[rb*16+r][kq*8..+8].
// ---------------------------------------------------------------------------
__global__ __launch_bounds__(256)
void split_frag(const float* __restrict__ in, unsigned short* __restrict__ hi,
                unsigned short* __restrict__ lo, int R, int K8, int total) {
  int idx = blockIdx.x * 256 + threadIdx.x;
  if (idx >= total) return;
  int r = idx & 15;
  int t = idx >> 4;
  int kq = t % K8;
  int rb = t / K8;
  int row = rb * 16 + r;
  float v[8] = {0.f, 0.f, 0.f, 0.f, 0.f, 0.f, 0.f, 0.f};
  if (row < R) {
    const float* p = in + (size_t)row * (K8 * 8) + kq * 8;
    float4 a = *(const float4*)p;
    float4 b = *(const float4*)(p + 4);
    v[0] = a.x; v[1] = a.y; v[2] = a.z; v[3] = a.w;
    v[4] = b.x; v[5] = b.y; v[6] = b.z; v[7] = b.w;
  }
  union { unsigned short u[8]; int4 v4; } H, L;
  #pragma unroll
  for (int e = 0; e < 8; ++e) {
    unsigned short hb_ = f2bf_rne(v[e]);
    H.u[e] = hb_;
    L.u[e] = f2bf_rne(v[e] - bf2f(hb_));
  }
  *(int4*)&hi[(size_t)idx * 8] = H.v4;
  *(int4*)&lo[(size_t)idx * 8] = L.v4;
}

// ---------------------------------------------------------------------------
// LDS-free split-bf16 MFMA GEMM (R8 config — best measured: 44.4us, MfmaUtil
// 28%): block = 64 rows x 128 cols (one full head), 2 waves sharing A-frags
// (L1 reuse), single-buffered 16 b128 loads + 48 MFMAs per K-32 per wave.
// Grid 160*8 swizzled: blk%8 == mtile%8 (XCD L2 A-affinity).
// NOTE (R11 post-mortem): smaller tiles raise occupancy but halve per-wave
// arithmetic intensity -> MfmaUtil 13% and 2x slower. Do not shrink tile.
// ---------------------------------------------------------------------------
__global__ __launch_bounds__(128, 3)
void gemm_frag(const unsigned short* __restrict__ Afh,
               const unsigned short* __restrict__ Afl,
               const unsigned short* __restrict__ Bfh,
               const unsigned short* __restrict__ Bfl,
               const float* __restrict__ avec,
               unsigned short* __restrict__ hb,
               float* __restrict__ si, float* __restrict__ sj,
               int M, int K) {
  __shared__ float rsi[64][2];
  __shared__ float rsj[64][2];
  int tid = threadIdx.x;
  int wave = tid >> 6, lane = tid & 63;
  int r = lane & 15, q = lane >> 4;

  int blk = blockIdx.x;
  int rr = blk & 7, gg = blk >> 3;
  int head = gg & 7;
  int mtile = (gg >> 3) * 8 + rr;     // blk%8 == mtile%8 -> XCD affinity
  int m0 = mtile * 64;
  int wn = wave * 64;
  int K8 = K >> 3;

  const bf16x8* pAh = (const bf16x8*)Afh;
  const bf16x8* pAl = (const bf16x8*)Afl;
  const bf16x8* pBh = (const bf16x8*)Bfh;
  const bf16x8* pBl = (const bf16x8*)Bfl;
  size_t rstep = (size_t)K8 * 16;
  size_t aidx = (size_t)(m0 >> 4) * rstep + (size_t)q * 16 + r;
  size_t bidx = (size_t)(head * 8 + (wn >> 4)) * rstep + (size_t)q * 16 + r;

  f32x4 acc[4][4] = {};

  for (int k0 = 0; k0 < K; k0 += 32, aidx += 64, bidx += 64) {
    bf16x8 ah[4], al[4], bh[4], bl[4];
    #pragma unroll
    for (int i = 0; i < 4; ++i) {
      ah[i] = pAh[aidx + i * rstep];
      al[i] = pAl[aidx + i * rstep];
      bh[i] = pBh[bidx + i * rstep];
      bl[i] = pBl[bidx + i * rstep];
    }
    #pragma unroll
    for (int i = 0; i < 4; ++i)
      #pragma unroll
      for (int j = 0; j < 4; ++j) {
        acc[i][j] = __builtin_amdgcn_mfma_f32_16x16x32_bf16(ah[i], bh[j], acc[i][j], 0, 0, 0);
        acc[i][j] = __builtin_amdgcn_mfma_f32_16x16x32_bf16(ah[i], bl[j], acc[i][j], 0, 0, 0);
        acc[i][j] = __builtin_amdgcn_mfma_f32_16x16x32_bf16(al[i], bh[j], acc[i][j], 0, 0, 0);
      }
  }

  // --- epilogue: C/D layout col = r, row = q*4 + reg (per 16x16 frag) ---
  const float* av = avec + (size_t)head * (2 * HID);
  float aiv[4], ajv[4];
  #pragma unroll
  for (int j = 0; j < 4; ++j) {
    int c = wn + j * 16 + r;
    aiv[j] = av[c];
    ajv[j] = av[HID + c];
  }
  #pragma unroll
  for (int i = 0; i < 4; ++i) {
    #pragma unroll
    for (int reg = 0; reg < 4; ++reg) {
      int lrow = i * 16 + q * 4 + reg;
      int row = m0 + lrow;
      float vsi = 0.f, vsj = 0.f;
      #pragma unroll
      for (int j = 0; j < 4; ++j) {
        float v = acc[i][j][reg];
        vsi = fmaf(v, aiv[j], vsi);
        vsj = fmaf(v, ajv[j], vsj);
        if (row < M)
          hb[((size_t)head * M + row) * HID + wn + j * 16 + r] = f2bf_rne(v);
      }
      #pragma unroll
      for (int o = 8; o >= 1; o >>= 1) {
        vsi += __shfl_xor(vsi, o);
        vsj += __shfl_xor(vsj, o);
      }
      if (r == 0) {
        rsi[lrow][wave] = vsi;
        rsj[lrow][wave] = vsj;
      }
    }
  }
  __syncthreads();
  if (tid < 64) {
    int row = m0 + tid;
    if (row < M) {
      si[(size_t)row * HEADS + head] = rsi[tid][0] + rsi[tid][1];
      sj[(size_t)row * HEADS + head] = rsj[tid][0] + rsj[tid][1];
    }
  }
}

// ---------------------------------------------------------------------------
// CSR build
// ---------------------------------------------------------------------------
__global__ void count_kernel(const int* __restrict__ dst, int* __restrict__ deg, int E) {
  int e = blockIdx.x * blockDim.x + threadIdx.x;
  if (e < E) atomicAdd(&deg[dst[e]], 1);
}

__global__ __launch_bounds__(1024)
void scan_kernel(const int* __restrict__ deg, int* __restrict__ off, int N) {
  __shared__ int sums[1024];
  const int PER = 10;
  int tid = threadIdx.x;
  int base = tid * PER;
  int loc[PER];
  int run = 0;
  #pragma unroll
  for (int j = 0; j < PER; ++j) {
    int v = (base + j < N) ? deg[base + j] : 0;
    run += v;
    loc[j] = run;
  }
  sums[tid] = run;
  __syncthreads();
  for (int o = 1; o < 1024; o <<= 1) {
    int v = (tid >= o) ? sums[tid - o] : 0;
    __syncthreads();
    sums[tid] += v;
    __syncthreads();
  }
  int ex = sums[tid] - run;
  if (tid == 0) off[0] = 0;
  #pragma unroll
  for (int j = 0; j < PER; ++j)
    if (base + j < N) off[base + j + 1] = ex + loc[j];
}

__global__ void fill_kernel(const int* __restrict__ src, const int* __restrict__ dst,
                            const int* __restrict__ off, int* __restrict__ cursor,
                            int* __restrict__ ssrc, int E) {
  int e = blockIdx.x * blockDim.x + threadIdx.x;
  if (e < E) {
    int d = dst[e];
    int p = atomicAdd(&cursor[d], 1);
    ssrc[off[d] + p] = src[e];
  }
}

// ---------------------------------------------------------------------------
// Edge softmax weights: one wave per dst node, lane = eidx*8 + head.
// ---------------------------------------------------------------------------
__global__ __launch_bounds__(256)
void alpha_kernel(const float* __restrict__ si, const float* __restrict__ sj,
                  const int* __restrict__ off, const int* __restrict__ ssrc,
                  float* __restrict__ w, float* __restrict__ invden, int N) {
  int wv = (blockIdx.x * blockDim.x + threadIdx.x) >> 6;
  if (wv >= N) return;
  int lane = threadIdx.x & 63;
  int eidx = lane >> 3, head = lane & 7;
  int begin = off[wv], end = off[wv + 1];
  float s_i = si[wv * HEADS + head];

  float m = -INFINITY;
  for (int k0 = begin; k0 < end; k0 += 8) {
    int k = k0 + eidx;
    if (k < end) {
      float e = s_i + sj[ssrc[k] * HEADS + head];
      e = e > 0.f ? e : 0.01f * e;
      m = fmaxf(m, e);
    }
  }
  m = fmaxf(m, __shfl_xor(m, 8));
  m = fmaxf(m, __shfl_xor(m, 16));
  m = fmaxf(m, __shfl_xor(m, 32));

  float sum = 0.f;
  for (int k0 = begin; k0 < end; k0 += 8) {
    int k = k0 + eidx;
    if (k < end) {
      float e = s_i + sj[ssrc[k] * HEADS + head];
      e = e > 0.f ? e : 0.01f * e;
      float wt = expf(e - m);
      w[(size_t)k * HEADS + head] = wt;
      sum += wt;
    }
  }
  sum += __shfl_xor(sum, 8);
  sum += __shfl_xor(sum, 16);
  sum += __shfl_xor(sum, 32);
  if (eidx == 0)
    invden[wv * HEADS + head] = sum > 0.f ? 1.0f / sum : 0.f;
}

// ---------------------------------------------------------------------------
// Aggregation: one wave per (dst, head); head = blockIdx.x & 7 (XCD/L2
// affinity). Wave = 4 groups x 16 lanes; 16 edge-vectors in flight.
// Output aggbuf is bf16 (halves the HBM round-trip).
// ---------------------------------------------------------------------------
__global__ __launch_bounds__(512)
void gat_aggregate3(const unsigned short* __restrict__ hb,
                    const float* __restrict__ w, const float* __restrict__ invden,
                    const int* __restrict__ off, const int* __restrict__ ssrc,
                    unsigned short* __restrict__ aggb, int N) {
  int head = blockIdx.x & 7;
  int n = (blockIdx.x >> 3) * 8 + (threadIdx.x >> 6);
  if (n >= N) return;
  int lane = threadIdx.x & 63;
  int grp = lane >> 4;
  int l = lane & 15;
  const unsigned short* hbase = hb + (size_t)head * N * HID;
  int begin = off[n], end = off[n + 1];

  float a0 = 0.f, a1 = 0.f, a2 = 0.f, a3 = 0.f;
  float a4 = 0.f, a5 = 0.f, a6 = 0.f, a7 = 0.f;

  for (int k0 = begin; k0 < end; k0 += 16) {
    int kk[4];
    float wv[4];
    int sv[4];
    #pragma unroll
    for (int u = 0; u < 4; ++u) {
      int k = k0 + u * 4 + grp;
      kk[u] = k < end ? k : begin;
      sv[u] = ssrc[kk[u]];
      wv[u] = w[(size_t)kk[u] * HEADS + head];
      if (k >= end) wv[u] = 0.f;
    }
    int4 pv[4];
    #pragma unroll
    for (int u = 0; u < 4; ++u)
      pv[u] = *(const int4*)&hbase[(size_t)sv[u] * HID + l * 8];
    #pragma unroll
    for (int u = 0; u < 4; ++u) {
      float wu = wv[u];
      int4 p = pv[u];
      a0 = fmaf(wu, bf2f((unsigned)p.x & 0xffffu), a0);
      a1 = fmaf(wu, __uint_as_float((unsigned)p.x & 0xffff0000u), a1);
      a2 = fmaf(wu, bf2f((unsigned)p.y & 0xffffu), a2);
      a3 = fmaf(wu, __uint_as_float((unsigned)p.y & 0xffff0000u), a3);
      a4 = fmaf(wu, bf2f((unsigned)p.z & 0xffffu), a4);
      a5 = fmaf(wu, __uint_as_float((unsigned)p.z & 0xffff0000u), a5);
      a6 = fmaf(wu, bf2f((unsigned)p.w & 0xffffu), a6);
      a7 = fmaf(wu, __uint_as_float((unsigned)p.w & 0xffff0000u), a7);
    }
  }
  a0 += __shfl_xor(a0, 16); a1 += __shfl_xor(a1, 16);
  a2 += __shfl_xor(a2, 16); a3 += __shfl_xor(a3, 16);
  a4 += __shfl_xor(a4, 16); a5 += __shfl_xor(a5, 16);
  a6 += __shfl_xor(a6, 16); a7 += __shfl_xor(a7, 16);
  a0 += __shfl_xor(a0, 32); a1 += __shfl_xor(a1, 32);
  a2 += __shfl_xor(a2, 32); a3 += __shfl_xor(a3, 32);
  a4 += __shfl_xor(a4, 32); a5 += __shfl_xor(a5, 32);
  a6 += __shfl_xor(a6, 32); a7 += __shfl_xor(a7, 32);

  if (grp == 0) {
    float inv = invden[n * HEADS + head];
    union { unsigned short u[8]; int4 v4; } P;
    P.u[0] = f2bf_rne(a0 * inv); P.u[1] = f2bf_rne(a1 * inv);
    P.u[2] = f2bf_rne(a2 * inv); P.u[3] = f2bf_rne(a3 * inv);
    P.u[4] = f2bf_rne(a4 * inv); P.u[5] = f2bf_rne(a5 * inv);
    P.u[6] = f2bf_rne(a6 * inv); P.u[7] = f2bf_rne(a7 * inv);
    *(int4*)&aggb[((size_t)head * N + n) * HID + l * 8] = P.v4;
  }
}

// ---------------------------------------------------------------------------
// Head mean + ELU (bf16 aggbuf), writing layer-2 A in frag-major split form
// ---------------------------------------------------------------------------
__global__ __launch_bounds__(256)
void headmean_frag(const unsigned short* __restrict__ aggb,
                   unsigned short* __restrict__ hi, unsigned short* __restrict__ lo,
                   int N) {
  int idx = blockIdx.x * 256 + threadIdx.x;   // (rb,kq,r), K8=16
  int total = ((N + 15) / 16) * 256;
  if (idx >= total) return;
  int r = idx & 15;
  int kq = (idx >> 4) & 15;
  int rb = idx >> 8;
  int n = rb * 16 + r;
  float s[8] = {0.f, 0.f, 0.f, 0.f, 0.f, 0.f, 0.f, 0.f};
  if (n < N) {
    #pragma unroll
    for (int hh = 0; hh < HEADS; ++hh) {
      int4 pv = *(const int4*)&aggb[((size_t)hh * N + n) * HID + kq * 8];
      s[0] += bf2f((unsigned)pv.x & 0xffffu);
      s[1] += __uint_as_float((unsigned)pv.x & 0xffff0000u);
      s[2] += bf2f((unsigned)pv.y & 0xffffu);
      s[3] += __uint_as_float((unsigned)pv.y & 0xffff0000u);
      s[4] += bf2f((unsigned)pv.z & 0xffffu);
      s[5] += __uint_as_float((unsigned)pv.z & 0xffff0000u);
      s[6] += bf2f((unsigned)pv.w & 0xffffu);
      s[7] += __uint_as_float((unsigned)pv.w & 0xffff0000u);
    }
  }
  union { unsigned short u[8]; int4 v4; } H, L;
  #pragma unroll
  for (int e = 0; e < 8; ++e) {
    float v = s[e] * (1.0f / HEADS);
    v = v > 0.f ? v : (expf(v) - 1.0f);   // ELU
    unsigned short hb_ = f2bf_rne(v);
    H.u[e] = hb_;
    L.u[e] = f2bf_rne(v - bf2f(hb_));
  }
  *(int4*)&hi[(size_t)idx * 8] = H.v4;
  *(int4*)&lo[(size_t)idx * 8] = L.v4;
}

// ---------------------------------------------------------------------------
// Layer-2 tail: head mean + ELU + graph pooling fused (no emb2 materialized).
// ---------------------------------------------------------------------------
__global__ __launch_bounds__(256)
void headmean_pool(const unsigned short* __restrict__ aggb, float* __restrict__ g,
                   int N) {
  __shared__ float sm[16][128];
  int t = threadIdx.x;
  int nl = t >> 4, dg = t & 15;
  int n = blockIdx.x * 16 + nl;
  float v[8] = {0.f, 0.f, 0.f, 0.f, 0.f, 0.f, 0.f, 0.f};
  if (n < N) {
    #pragma unroll
    for (int hh = 0; hh < HEADS; ++hh) {
      int4 pv = *(const int4*)&aggb[((size_t)hh * N + n) * HID + dg * 8];
      v[0] += bf2f((unsigned)pv.x & 0xffffu);
      v[1] += __uint_as_float((unsigned)pv.x & 0xffff0000u);
      v[2] += bf2f((unsigned)pv.y & 0xffffu);
      v[3] += __uint_as_float((unsigned)pv.y & 0xffff0000u);
      v[4] += bf2f((unsigned)pv.z & 0xffffu);
      v[5] += __uint_as_float((unsigned)pv.z & 0xffff0000u);
      v[6] += bf2f((unsigned)pv.w & 0xffffu);
      v[7] += __uint_as_float((unsigned)pv.w & 0xffff0000u);
    }
    #pragma unroll
    for (int e = 0; e < 8; ++e) {
      float x = v[e] * (1.0f / HEADS);
      v[e] = x > 0.f ? x : (expf(x) - 1.0f);   // ELU
    }
  }
  #pragma unroll
  for (int e = 0; e < 8; ++e) sm[nl][dg * 8 + e] = v[e];
  __syncthreads();
  if (t < 128) {
    float s = 0.f;
    #pragma unroll
    for (int nn = 0; nn < 16; ++nn) s += sm[nn][t];
    atomicAdd(&g[t], s);
  }
}

// ---------------------------------------------------------------------------
// LayerNorm + MLP head
// ---------------------------------------------------------------------------
__global__ __launch_bounds__(128)
void mlp_kernel(const float* __restrict__ g, const float* __restrict__ ln_g,
                const float* __restrict__ ln_b, const float* __restrict__ Wl1,
                const float* __restrict__ bl1, const float* __restrict__ Wl2,
                const float* __restrict__ bl2, const float* __restrict__ Wl3,
                const float* __restrict__ bl3, float* __restrict__ out, float invN) {
  __shared__ float red[128];
  __shared__ float gn[128];
  __shared__ float x1[64];
  __shared__ float x2[16];
  int t = threadIdx.x;
  float gg = g[t] * invN;
  red[t] = gg;
  __syncthreads();
  for (int o = 64; o > 0; o >>= 1) {
    if (t < o) red[t] += red[t + o];
    __syncthreads();
  }
  float mu = red[0] * (1.0f / HID);
  __syncthreads();
  float dv = gg - mu;
  red[t] = dv * dv;
  __syncthreads();
  for (int o = 64; o > 0; o >>= 1) {
    if (t < o) red[t] += red[t + o];
    __syncthreads();
  }
  float var = red[0] * (1.0f / HID);
  gn[t] = dv / sqrtf(var + 1e-5f) * ln_g[t] + ln_b[t];
  __syncthreads();
  if (t < 64) {
    float s = bl1[t];
    for (int k = 0; k < 128; ++k) s += Wl1[t * 128 + k] * gn[k];
    x1[t] = s > 0.f ? s : 0.01f * s;
  }
  __syncthreads();
  if (t < 16) {
    float s = bl2[t];
    for (int k = 0; k < 64; ++k) s += Wl2[t * 64 + k] * x1[k];
    x2[t] = s > 0.f ? s : 0.01f * s;
  }
  __syncthreads();
  if (t < 16) {
    float s = bl3[t];
    for (int k = 0; k < 16; ++k) s += Wl3[t * 16 + k] * x2[k];
    out[t] = s > 0.f ? s : 0.f;
  }
}

// ---------------------------------------------------------------------------
extern "C" void kernel_launch(void* const* d_in, const int* in_sizes, int n_in,
                              void* d_out, int out_size, void* d_ws, size_t ws_size,
                              hipStream_t stream) {
  const float* x    = (const float*)d_in[0];
  const int*   esrc = (const int*)d_in[1];
  const int*   edst = (const int*)d_in[2];
  const float* W1   = (const float*)d_in[3];
  const float* a1   = (const float*)d_in[4];
  const float* W2   = (const float*)d_in[5];
  const float* a2   = (const float*)d_in[6];
  const float* ln_g = (const float*)d_in[7];
  const float* ln_b = (const float*)d_in[8];
  const float* Wl1  = (const float*)d_in[9];
  const float* bl1  = (const float*)d_in[10];
  const float* Wl2  = (const float*)d_in[11];
  const float* bl2  = (const float*)d_in[12];
  const float* Wl3  = (const float*)d_in[13];
  const float* bl3  = (const float*)d_in[14];
  float* out = (float*)d_out;

  const int RBPAD = 640;  // row-blocks padded (10240 rows) for in-bounds frags

  // workspace carve-up
  unsigned short* aggb = (unsigned short*)d_ws;                 // 20.5 MB
  float* si   = (float*)(aggb + (size_t)N_NODES * HEADS * HID); // 80,000
  float* sj   = si + N_NODES * HEADS;                           // 80,000
  float* g    = sj + N_NODES * HEADS;                           // 128
  float* wbuf = g + 128;                                        // 1,280,000
  float* invd = wbuf + (size_t)N_EDGES * HEADS;                 // 80,000
  int*   deg  = (int*)(invd + N_NODES * HEADS);                 // 10,000
  int*   cur  = deg + N_NODES;                                  // 10,000
  int*   off  = cur + N_NODES;                                  // 10,001 -> pad 10,004
  int*   ssrc = off + 10004;                                    // 160,000
  unsigned short* Afh = (unsigned short*)(ssrc + N_EDGES);      // 640*64*128 us
  unsigned short* Afl = Afh + (size_t)RBPAD * 64 * 128;
  unsigned short* Bfh = Afl + (size_t)RBPAD * 64 * 128;
  unsigned short* Bfl = Bfh + (size_t)64 * 64 * 128;
  unsigned short* hb  = Bfl + (size_t)64 * 64 * 128;            // 20.5 MB

  // CSR by dst (deg+cursor zeroed in ONE memset)
  hipMemsetAsync(deg, 0, 2 * N_NODES * sizeof(int), stream);
  count_kernel<<<(N_EDGES + 255) / 256, 256, 0, stream>>>(edst, deg, N_EDGES);
  scan_kernel<<<1, 1024, 0, stream>>>(deg, off, N_NODES);
  fill_kernel<<<(N_EDGES + 255) / 256, 256, 0, stream>>>(esrc, edst, off, cur, ssrc, N_EDGES);

  hipMemsetAsync(g, 0, 128 * sizeof(float), stream);

  int gemmGrid = 160 * HEADS;                 // 1280 blocks of 128 threads
  int aggGrid = (N_NODES / 8) * 8;

  // ---- Layer 1 ----
  {
    int totalA = RBPAD * 64 * 16;             // 16B units, K8=64
    split_frag<<<(totalA + 255) / 256, 256, 0, stream>>>(x, Afh, Afl, N_NODES, 64, totalA);
    int totalB = 64 * 64 * 16;                // 1024 rows, K8=64
    split_frag<<<(totalB + 255) / 256, 256, 0, stream>>>(W1, Bfh, Bfl, HEADS * HID, 64, totalB);
    gemm_frag<<<gemmGrid, 128, 0, stream>>>(Afh, Afl, Bfh, Bfl, a1, hb,
                                            si, sj, N_NODES, N_FEAT);
  }
  alpha_kernel<<<(N_NODES + 3) / 4, 256, 0, stream>>>(si, sj, off, ssrc, wbuf, invd, N_NODES);
  gat_aggregate3<<<aggGrid, 512, 0, stream>>>(hb, wbuf, invd, off, ssrc, aggb, N_NODES);
  {
    int totalHM = ((N_NODES + 15) / 16) * 256;
    headmean_frag<<<(totalHM + 255) / 256, 256, 0, stream>>>(aggb, Afh, Afl, N_NODES);
  }

  // ---- Layer 2 ----
  {
    int totalB = 64 * 16 * 16;                // 1024 rows, K8=16
    split_frag<<<(totalB + 255) / 256, 256, 0, stream>>>(W2, Bfh, Bfl, HEADS * HID, 16, totalB);
    gemm_frag<<<gemmGrid, 128, 0, stream>>>(Afh, Afl, Bfh, Bfl, a2, hb,
                                            si, sj, N_NODES, HID);
  }
  alpha_kernel<<<(N_NODES + 3) / 4, 256, 0, stream>>>(si, sj, off, ssrc, wbuf, invd, N_NODES);
  gat_aggregate3<<<aggGrid, 512, 0, stream>>>(hb, wbuf, invd, off, ssrc, aggb, N_NODES);

  // ---- fused head-mean + pooling + MLP head ----
  headmean_pool<<<(N_NODES + 15) / 16, 256, 0, stream>>>(aggb, g, N_NODES);
  mlp_kernel<<<1, 128, 0, stream>>>(g, ln_g, ln_b, Wl1, bl1, Wl2, bl2, Wl3, bl3,
                                    out, 1.0f / N_NODES);
}

// Round 13
// 311.169 us; speedup vs baseline: 1.2649x; 1.0215x over previous
//
#include <hip/hip_runtime.h>
#include <math.h>

#define N_NODES 10000
#define N_EDGES 160000
#define N_FEAT  512
#define HEADS   8
#define HID     128

typedef __attribute__((ext_vector_type(8))) short bf16x8;
typedef __attribute__((ext_vector_type(4))) float f32x4;

// ---------------------------------------------------------------------------
// fp32 <-> bf16 helpers
// ---------------------------------------------------------------------------
__device__ inline unsigned short f2bf_rne(float f) {
  unsigned int u = __float_as_uint(f);
  unsigned int r = u + 0x7fffu + ((u >> 16) & 1u);
  return (unsigned short)(r >> 16);
}
__device__ inline float bf2f(unsigned int b) {
  return __uint_as_float(b << 16);
}

// ---------------------------------------------------------------------------
// Split fp32 [R][K] into hi/lo bf16 in MFMA-fragment-major layout:
// unit (rb,kq,r) at index (rb*K8+kq)*16+r holds 8 bf16 = A[rb*16+r][kq*8..+8].
// ---------------------------------------------------------------------------
__global__ __launch_bounds__(256)
void split_frag(const float* __restrict__ in, unsigned short* __restrict__ hi,
                unsigned short* __restrict__ lo, int R, int K8, int total) {
  int idx = blockIdx.x * 256 + threadIdx.x;
  if (idx >= total) return;
  int r = idx & 15;
  int t = idx >> 4;
  int kq = t % K8;
  int rb = t / K8;
  int row = rb * 16 + r;
  float v[8] = {0.f, 0.f, 0.f, 0.f, 0.f, 0.f, 0.f, 0.f};
  if (row < R) {
    const float* p = in + (size_t)row * (K8 * 8) + kq * 8;
    float4 a = *(const float4*)p;
    float4 b = *(const float4*)(p + 4);
    v[0] = a.x; v[1] = a.y; v[2] = a.z; v[3] = a.w;
    v[4] = b.x; v[5] = b.y; v[6] = b.z; v[7] = b.w;
  }
  union { unsigned short u[8]; int4 v4; } H, L;
  #pragma unroll
  for (int e = 0; e < 8; ++e) {
    unsigned short hb_ = f2bf_rne(v[e]);
    H.u[e] = hb_;
    L.u[e] = f2bf_rne(v[e] - bf2f(hb_));
  }
  *(int4*)&hi[(size_t)idx * 8] = H.v4;
  *(int4*)&lo[(size_t)idx * 8] = L.v4;
}

// ---------------------------------------------------------------------------
// LDS-free split-bf16 MFMA GEMM (R8 config — best measured: ~45us, MfmaUtil
// 28%): block = 64 rows x 128 cols (one full head), 2 waves sharing A-frags
// (L1 reuse), single-buffered 16 b128 loads + 48 MFMAs per K-32 per wave.
// Grid 160*8 swizzled: blk%8 == mtile%8 (XCD L2 A-affinity).
// NOTE (R11): smaller tiles raise occupancy but halve per-wave arithmetic
// intensity -> MfmaUtil 13% and 2x slower. NOTE (R10): register double-buffer
// is neutral and doubles VGPR. Do not change tile/buffering.
// ---------------------------------------------------------------------------
__global__ __launch_bounds__(128, 3)
void gemm_frag(const unsigned short* __restrict__ Afh,
               const unsigned short* __restrict__ Afl,
               const unsigned short* __restrict__ Bfh,
               const unsigned short* __restrict__ Bfl,
               const float* __restrict__ avec,
               unsigned short* __restrict__ hb,
               float* __restrict__ si, float* __restrict__ sj,
               int M, int K) {
  __shared__ float rsi[64][2];
  __shared__ float rsj[64][2];
  int tid = threadIdx.x;
  int wave = tid >> 6, lane = tid & 63;
  int r = lane & 15, q = lane >> 4;

  int blk = blockIdx.x;
  int rr = blk & 7, gg = blk >> 3;
  int head = gg & 7;
  int mtile = (gg >> 3) * 8 + rr;     // blk%8 == mtile%8 -> XCD affinity
  int m0 = mtile * 64;
  int wn = wave * 64;
  int K8 = K >> 3;

  const bf16x8* pAh = (const bf16x8*)Afh;
  const bf16x8* pAl = (const bf16x8*)Afl;
  const bf16x8* pBh = (const bf16x8*)Bfh;
  const bf16x8* pBl = (const bf16x8*)Bfl;
  size_t rstep = (size_t)K8 * 16;
  size_t aidx = (size_t)(m0 >> 4) * rstep + (size_t)q * 16 + r;
  size_t bidx = (size_t)(head * 8 + (wn >> 4)) * rstep + (size_t)q * 16 + r;

  f32x4 acc[4][4] = {};

  for (int k0 = 0; k0 < K; k0 += 32, aidx += 64, bidx += 64) {
    bf16x8 ah[4], al[4], bh[4], bl[4];
    #pragma unroll
    for (int i = 0; i < 4; ++i) {
      ah[i] = pAh[aidx + i * rstep];
      al[i] = pAl[aidx + i * rstep];
      bh[i] = pBh[bidx + i * rstep];
      bl[i] = pBl[bidx + i * rstep];
    }
    #pragma unroll
    for (int i = 0; i < 4; ++i)
      #pragma unroll
      for (int j = 0; j < 4; ++j) {
        acc[i][j] = __builtin_amdgcn_mfma_f32_16x16x32_bf16(ah[i], bh[j], acc[i][j], 0, 0, 0);
        acc[i][j] = __builtin_amdgcn_mfma_f32_16x16x32_bf16(ah[i], bl[j], acc[i][j], 0, 0, 0);
        acc[i][j] = __builtin_amdgcn_mfma_f32_16x16x32_bf16(al[i], bh[j], acc[i][j], 0, 0, 0);
      }
  }

  // --- epilogue: C/D layout col = r, row = q*4 + reg (per 16x16 frag) ---
  const float* av = avec + (size_t)head * (2 * HID);
  float aiv[4], ajv[4];
  #pragma unroll
  for (int j = 0; j < 4; ++j) {
    int c = wn + j * 16 + r;
    aiv[j] = av[c];
    ajv[j] = av[HID + c];
  }
  #pragma unroll
  for (int i = 0; i < 4; ++i) {
    #pragma unroll
    for (int reg = 0; reg < 4; ++reg) {
      int lrow = i * 16 + q * 4 + reg;
      int row = m0 + lrow;
      float vsi = 0.f, vsj = 0.f;
      #pragma unroll
      for (int j = 0; j < 4; ++j) {
        float v = acc[i][j][reg];
        vsi = fmaf(v, aiv[j], vsi);
        vsj = fmaf(v, ajv[j], vsj);
        if (row < M)
          hb[((size_t)head * M + row) * HID + wn + j * 16 + r] = f2bf_rne(v);
      }
      #pragma unroll
      for (int o = 8; o >= 1; o >>= 1) {
        vsi += __shfl_xor(vsi, o);
        vsj += __shfl_xor(vsj, o);
      }
      if (r == 0) {
        rsi[lrow][wave] = vsi;
        rsj[lrow][wave] = vsj;
      }
    }
  }
  __syncthreads();
  if (tid < 64) {
    int row = m0 + tid;
    if (row < M) {
      si[(size_t)row * HEADS + head] = rsi[tid][0] + rsi[tid][1];
      sj[(size_t)row * HEADS + head] = rsj[tid][0] + rsj[tid][1];
    }
  }
}

// ---------------------------------------------------------------------------
// CSR build
// ---------------------------------------------------------------------------
__global__ void count_kernel(const int* __restrict__ dst, int* __restrict__ deg, int E) {
  int e = blockIdx.x * blockDim.x + threadIdx.x;
  if (e < E) atomicAdd(&deg[dst[e]], 1);
}

__global__ __launch_bounds__(1024)
void scan_kernel(const int* __restrict__ deg, int* __restrict__ off, int N) {
  __shared__ int sums[1024];
  const int PER = 10;
  int tid = threadIdx.x;
  int base = tid * PER;
  int loc[PER];
  int run = 0;
  #pragma unroll
  for (int j = 0; j < PER; ++j) {
    int v = (base + j < N) ? deg[base + j] : 0;
    run += v;
    loc[j] = run;
  }
  sums[tid] = run;
  __syncthreads();
  for (int o = 1; o < 1024; o <<= 1) {
    int v = (tid >= o) ? sums[tid - o] : 0;
    __syncthreads();
    sums[tid] += v;
    __syncthreads();
  }
  int ex = sums[tid] - run;
  if (tid == 0) off[0] = 0;
  #pragma unroll
  for (int j = 0; j < PER; ++j)
    if (base + j < N) off[base + j + 1] = ex + loc[j];
}

__global__ void fill_kernel(const int* __restrict__ src, const int* __restrict__ dst,
                            const int* __restrict__ off, int* __restrict__ cursor,
                            int* __restrict__ ssrc, int E) {
  int e = blockIdx.x * blockDim.x + threadIdx.x;
  if (e < E) {
    int d = dst[e];
    int p = atomicAdd(&cursor[d], 1);
    ssrc[off[d] + p] = src[e];
  }
}

// ---------------------------------------------------------------------------
// FUSED softmax + aggregation: one wave per (dst, head); head = blockIdx.x&7
// (XCD/L2 affinity on head-major hb).
// Phase 1 (64 lanes = 64 edges): one exp per (edge,head); (src, w) stay in
// registers; wave shfl-reduce for max and denom. Gather phase pulls each
// edge's (w, src) via __shfl (register, ~4cyc) instead of two dependent L2
// loads — this is R9's fusion done without the 16x redundant exp.
// deg>64 tail: rare recompute loop (Poisson λ=16).
// ---------------------------------------------------------------------------
__global__ __launch_bounds__(512)
void gat_aggregate5(const unsigned short* __restrict__ hb,
                    const float* __restrict__ si, const float* __restrict__ sj,
                    const int* __restrict__ off, const int* __restrict__ ssrc,
                    unsigned short* __restrict__ aggb, int N) {
  int head = blockIdx.x & 7;
  int n = (blockIdx.x >> 3) * 8 + (threadIdx.x >> 6);
  if (n >= N) return;
  int lane = threadIdx.x & 63;
  int grp = lane >> 4;
  int l = lane & 15;
  const unsigned short* hbase = hb + (size_t)head * N * HID;
  int begin = off[n], end = off[n + 1];
  int deg = end - begin;
  int dmin = deg < 64 ? deg : 64;
  float s_i = si[n * HEADS + head];

  // --- phase 1: per-lane edge score; (src0, w0) register-resident ---
  int src0 = 0;
  float sc0 = -INFINITY;
  if (lane < deg) {
    src0 = ssrc[begin + lane];
    float t = s_i + sj[src0 * HEADS + head];
    sc0 = t > 0.f ? t : 0.01f * t;
  }
  float m = sc0;
  for (int e2 = 64 + lane; e2 < deg; e2 += 64) {     // rare tail max
    int s = ssrc[begin + e2];
    float t = s_i + sj[s * HEADS + head];
    t = t > 0.f ? t : 0.01f * t;
    m = fmaxf(m, t);
  }
  #pragma unroll
  for (int o = 1; o <= 32; o <<= 1) m = fmaxf(m, __shfl_xor(m, o));

  float w0 = (lane < deg) ? expf(sc0 - m) : 0.f;
  float den = w0;
  for (int e2 = 64 + lane; e2 < deg; e2 += 64) {     // rare tail denom
    int s = ssrc[begin + e2];
    float t = s_i + sj[s * HEADS + head];
    t = t > 0.f ? t : 0.01f * t;
    den += expf(t - m);
  }
  #pragma unroll
  for (int o = 1; o <= 32; o <<= 1) den += __shfl_xor(den, o);

  // --- gather phase: 4 groups x 16 lanes, 16 edges per iteration ---
  float a0 = 0.f, a1 = 0.f, a2 = 0.f, a3 = 0.f;
  float a4 = 0.f, a5 = 0.f, a6 = 0.f, a7 = 0.f;

  for (int e0 = 0; e0 < dmin; e0 += 16) {
    float we[4];
    int se[4];
    #pragma unroll
    for (int u = 0; u < 4; ++u) {
      int e = e0 + u * 4 + grp;
      float w_ = __shfl(w0, e);
      se[u] = __shfl(src0, e);
      we[u] = (e < dmin) ? w_ : 0.f;
    }
    int4 pv[4];
    #pragma unroll
    for (int u = 0; u < 4; ++u)
      pv[u] = *(const int4*)&hbase[(size_t)se[u] * HID + l * 8];
    #pragma unroll
    for (int u = 0; u < 4; ++u) {
      float wu = we[u];
      int4 p = pv[u];
      a0 = fmaf(wu, bf2f((unsigned)p.x & 0xffffu), a0);
      a1 = fmaf(wu, __uint_as_float((unsigned)p.x & 0xffff0000u), a1);
      a2 = fmaf(wu, bf2f((unsigned)p.y & 0xffffu), a2);
      a3 = fmaf(wu, __uint_as_float((unsigned)p.y & 0xffff0000u), a3);
      a4 = fmaf(wu, bf2f((unsigned)p.z & 0xffffu), a4);
      a5 = fmaf(wu, __uint_as_float((unsigned)p.z & 0xffff0000u), a5);
      a6 = fmaf(wu, bf2f((unsigned)p.w & 0xffffu), a6);
      a7 = fmaf(wu, __uint_as_float((unsigned)p.w & 0xffff0000u), a7);
    }
  }
  // rare tail: deg > 64, recompute weights per group
  for (int e2 = 64; e2 < deg; e2 += 4) {
    int e = e2 + grp;
    bool valid = e < deg;
    int s = ssrc[valid ? begin + e : begin];
    float t = s_i + sj[s * HEADS + head];
    t = t > 0.f ? t : 0.01f * t;
    float wu = valid ? expf(t - m) : 0.f;
    int4 p = *(const int4*)&hbase[(size_t)s * HID + l * 8];
    a0 = fmaf(wu, bf2f((unsigned)p.x & 0xffffu), a0);
    a1 = fmaf(wu, __uint_as_float((unsigned)p.x & 0xffff0000u), a1);
    a2 = fmaf(wu, bf2f((unsigned)p.y & 0xffffu), a2);
    a3 = fmaf(wu, __uint_as_float((unsigned)p.y & 0xffff0000u), a3);
    a4 = fmaf(wu, bf2f((unsigned)p.z & 0xffffu), a4);
    a5 = fmaf(wu, __uint_as_float((unsigned)p.z & 0xffff0000u), a5);
    a6 = fmaf(wu, bf2f((unsigned)p.w & 0xffffu), a6);
    a7 = fmaf(wu, __uint_as_float((unsigned)p.w & 0xffff0000u), a7);
  }

  a0 += __shfl_xor(a0, 16); a1 += __shfl_xor(a1, 16);
  a2 += __shfl_xor(a2, 16); a3 += __shfl_xor(a3, 16);
  a4 += __shfl_xor(a4, 16); a5 += __shfl_xor(a5, 16);
  a6 += __shfl_xor(a6, 16); a7 += __shfl_xor(a7, 16);
  a0 += __shfl_xor(a0, 32); a1 += __shfl_xor(a1, 32);
  a2 += __shfl_xor(a2, 32); a3 += __shfl_xor(a3, 32);
  a4 += __shfl_xor(a4, 32); a5 += __shfl_xor(a5, 32);
  a6 += __shfl_xor(a6, 32); a7 += __shfl_xor(a7, 32);

  if (grp == 0) {
    float inv = den > 0.f ? 1.0f / den : 0.f;
    union { unsigned short u[8]; int4 v4; } P;
    P.u[0] = f2bf_rne(a0 * inv); P.u[1] = f2bf_rne(a1 * inv);
    P.u[2] = f2bf_rne(a2 * inv); P.u[3] = f2bf_rne(a3 * inv);
    P.u[4] = f2bf_rne(a4 * inv); P.u[5] = f2bf_rne(a5 * inv);
    P.u[6] = f2bf_rne(a6 * inv); P.u[7] = f2bf_rne(a7 * inv);
    *(int4*)&aggb[((size_t)head * N + n) * HID + l * 8] = P.v4;
  }
}

// ---------------------------------------------------------------------------
// Head mean + ELU (bf16 aggbuf), writing layer-2 A in frag-major split form
// ---------------------------------------------------------------------------
__global__ __launch_bounds__(256)
void headmean_frag(const unsigned short* __restrict__ aggb,
                   unsigned short* __restrict__ hi, unsigned short* __restrict__ lo,
                   int N) {
  int idx = blockIdx.x * 256 + threadIdx.x;   // (rb,kq,r), K8=16
  int total = ((N + 15) / 16) * 256;
  if (idx >= total) return;
  int r = idx & 15;
  int kq = (idx >> 4) & 15;
  int rb = idx >> 8;
  int n = rb * 16 + r;
  float s[8] = {0.f, 0.f, 0.f, 0.f, 0.f, 0.f, 0.f, 0.f};
  if (n < N) {
    #pragma unroll
    for (int hh = 0; hh < HEADS; ++hh) {
      int4 pv = *(const int4*)&aggb[((size_t)hh * N + n) * HID + kq * 8];
      s[0] += bf2f((unsigned)pv.x & 0xffffu);
      s[1] += __uint_as_float((unsigned)pv.x & 0xffff0000u);
      s[2] += bf2f((unsigned)pv.y & 0xffffu);
      s[3] += __uint_as_float((unsigned)pv.y & 0xffff0000u);
      s[4] += bf2f((unsigned)pv.z & 0xffffu);
      s[5] += __uint_as_float((unsigned)pv.z & 0xffff0000u);
      s[6] += bf2f((unsigned)pv.w & 0xffffu);
      s[7] += __uint_as_float((unsigned)pv.w & 0xffff0000u);
    }
  }
  union { unsigned short u[8]; int4 v4; } H, L;
  #pragma unroll
  for (int e = 0; e < 8; ++e) {
    float v = s[e] * (1.0f / HEADS);
    v = v > 0.f ? v : (expf(v) - 1.0f);   // ELU
    unsigned short hb_ = f2bf_rne(v);
    H.u[e] = hb_;
    L.u[e] = f2bf_rne(v - bf2f(hb_));
  }
  *(int4*)&hi[(size_t)idx * 8] = H.v4;
  *(int4*)&lo[(size_t)idx * 8] = L.v4;
}

// ---------------------------------------------------------------------------
// Layer-2 tail: head mean + ELU + graph pooling fused (no emb2 materialized).
// ---------------------------------------------------------------------------
__global__ __launch_bounds__(256)
void headmean_pool(const unsigned short* __restrict__ aggb, float* __restrict__ g,
                   int N) {
  __shared__ float sm[16][128];
  int t = threadIdx.x;
  int nl = t >> 4, dg = t & 15;
  int n = blockIdx.x * 16 + nl;
  float v[8] = {0.f, 0.f, 0.f, 0.f, 0.f, 0.f, 0.f, 0.f};
  if (n < N) {
    #pragma unroll
    for (int hh = 0; hh < HEADS; ++hh) {
      int4 pv = *(const int4*)&aggb[((size_t)hh * N + n) * HID + dg * 8];
      v[0] += bf2f((unsigned)pv.x & 0xffffu);
      v[1] += __uint_as_float((unsigned)pv.x & 0xffff0000u);
      v[2] += bf2f((unsigned)pv.y & 0xffffu);
      v[3] += __uint_as_float((unsigned)pv.y & 0xffff0000u);
      v[4] += bf2f((unsigned)pv.z & 0xffffu);
      v[5] += __uint_as_float((unsigned)pv.z & 0xffff0000u);
      v[6] += bf2f((unsigned)pv.w & 0xffffu);
      v[7] += __uint_as_float((unsigned)pv.w & 0xffff0000u);
    }
    #pragma unroll
    for (int e = 0; e < 8; ++e) {
      float x = v[e] * (1.0f / HEADS);
      v[e] = x > 0.f ? x : (expf(x) - 1.0f);   // ELU
    }
  }
  #pragma unroll
  for (int e = 0; e < 8; ++e) sm[nl][dg * 8 + e] = v[e];
  __syncthreads();
  if (t < 128) {
    float s = 0.f;
    #pragma unroll
    for (int nn = 0; nn < 16; ++nn) s += sm[nn][t];
    atomicAdd(&g[t], s);
  }
}

// ---------------------------------------------------------------------------
// LayerNorm + MLP head
// ---------------------------------------------------------------------------
__global__ __launch_bounds__(128)
void mlp_kernel(const float* __restrict__ g, const float* __restrict__ ln_g,
                const float* __restrict__ ln_b, const float* __restrict__ Wl1,
                const float* __restrict__ bl1, const float* __restrict__ Wl2,
                const float* __restrict__ bl2, const float* __restrict__ Wl3,
                const float* __restrict__ bl3, float* __restrict__ out, float invN) {
  __shared__ float red[128];
  __shared__ float gn[128];
  __shared__ float x1[64];
  __shared__ float x2[16];
  int t = threadIdx.x;
  float gg = g[t] * invN;
  red[t] = gg;
  __syncthreads();
  for (int o = 64; o > 0; o >>= 1) {
    if (t < o) red[t] += red[t + o];
    __syncthreads();
  }
  float mu = red[0] * (1.0f / HID);
  __syncthreads();
  float dv = gg - mu;
  red[t] = dv * dv;
  __syncthreads();
  for (int o = 64; o > 0; o >>= 1) {
    if (t < o) red[t] += red[t + o];
    __syncthreads();
  }
  float var = red[0] * (1.0f / HID);
  gn[t] = dv / sqrtf(var + 1e-5f) * ln_g[t] + ln_b[t];
  __syncthreads();
  if (t < 64) {
    float s = bl1[t];
    for (int k = 0; k < 128; ++k) s += Wl1[t * 128 + k] * gn[k];
    x1[t] = s > 0.f ? s : 0.01f * s;
  }
  __syncthreads();
  if (t < 16) {
    float s = bl2[t];
    for (int k = 0; k < 64; ++k) s += Wl2[t * 64 + k] * x1[k];
    x2[t] = s > 0.f ? s : 0.01f * s;
  }
  __syncthreads();
  if (t < 16) {
    float s = bl3[t];
    for (int k = 0; k < 16; ++k) s += Wl3[t * 16 + k] * x2[k];
    out[t] = s > 0.f ? s : 0.f;
  }
}

// ---------------------------------------------------------------------------
extern "C" void kernel_launch(void* const* d_in, const int* in_sizes, int n_in,
                              void* d_out, int out_size, void* d_ws, size_t ws_size,
                              hipStream_t stream) {
  const float* x    = (const float*)d_in[0];
  const int*   esrc = (const int*)d_in[1];
  const int*   edst = (const int*)d_in[2];
  const float* W1   = (const float*)d_in[3];
  const float* a1   = (const float*)d_in[4];
  const float* W2   = (const float*)d_in[5];
  const float* a2   = (const float*)d_in[6];
  const float* ln_g = (const float*)d_in[7];
  const float* ln_b = (const float*)d_in[8];
  const float* Wl1  = (const float*)d_in[9];
  const float* bl1  = (const float*)d_in[10];
  const float* Wl2  = (const float*)d_in[11];
  const float* bl2  = (const float*)d_in[12];
  const float* Wl3  = (const float*)d_in[13];
  const float* bl3  = (const float*)d_in[14];
  float* out = (float*)d_out;

  const int RBPAD = 640;  // row-blocks padded (10240 rows) for in-bounds frags

  // workspace carve-up
  unsigned short* aggb = (unsigned short*)d_ws;                 // 20.5 MB
  float* si   = (float*)(aggb + (size_t)N_NODES * HEADS * HID); // 80,000
  float* sj   = si + N_NODES * HEADS;                           // 80,000
  float* g    = sj + N_NODES * HEADS;                           // 128
  int*   deg  = (int*)(g + 128);                                // 10,000
  int*   cur  = deg + N_NODES;                                  // 10,000
  int*   off  = cur + N_NODES;                                  // 10,001 -> pad 10,004
  int*   ssrc = off + 10004;                                    // 160,000
  unsigned short* Afh = (unsigned short*)(ssrc + N_EDGES);      // 640*64*128 us
  unsigned short* Afl = Afh + (size_t)RBPAD * 64 * 128;
  unsigned short* Bfh = Afl + (size_t)RBPAD * 64 * 128;
  unsigned short* Bfl = Bfh + (size_t)64 * 64 * 128;
  unsigned short* hb  = Bfl + (size_t)64 * 64 * 128;            // 20.5 MB

  // CSR by dst (deg+cursor zeroed in ONE memset)
  hipMemsetAsync(deg, 0, 2 * N_NODES * sizeof(int), stream);
  count_kernel<<<(N_EDGES + 255) / 256, 256, 0, stream>>>(edst, deg, N_EDGES);
  scan_kernel<<<1, 1024, 0, stream>>>(deg, off, N_NODES);
  fill_kernel<<<(N_EDGES + 255) / 256, 256, 0, stream>>>(esrc, edst, off, cur, ssrc, N_EDGES);

  hipMemsetAsync(g, 0, 128 * sizeof(float), stream);

  int gemmGrid = 160 * HEADS;                 // 1280 blocks of 128 threads
  int aggGrid = (N_NODES / 8) * 8;

  // ---- Layer 1 ----
  {
    int totalA = RBPAD * 64 * 16;             // 16B units, K8=64
    split_frag<<<(totalA + 255) / 256, 256, 0, stream>>>(x, Afh, Afl, N_NODES, 64, totalA);
    int totalB = 64 * 64 * 16;                // 1024 rows, K8=64
    split_frag<<<(totalB + 255) / 256, 256, 0, stream>>>(W1, Bfh, Bfl, HEADS * HID, 64, totalB);
    gemm_frag<<<gemmGrid, 128, 0, stream>>>(Afh, Afl, Bfh, Bfl, a1, hb,
                                            si, sj, N_NODES, N_FEAT);
  }
  gat_aggregate5<<<aggGrid, 512, 0, stream>>>(hb, si, sj, off, ssrc, aggb, N_NODES);
  {
    int totalHM = ((N_NODES + 15) / 16) * 256;
    headmean_frag<<<(totalHM + 255) / 256, 256, 0, stream>>>(aggb, Afh, Afl, N_NODES);
  }

  // ---- Layer 2 ----
  {
    int totalB = 64 * 16 * 16;                // 1024 rows, K8=16
    split_frag<<<(totalB + 255) / 256, 256, 0, stream>>>(W2, Bfh, Bfl, HEADS * HID, 16, totalB);
    gemm_frag<<<gemmGrid, 128, 0, stream>>>(Afh, Afl, Bfh, Bfl, a2, hb,
                                            si, sj, N_NODES, HID);
  }
  gat_aggregate5<<<aggGrid, 512, 0, stream>>>(hb, si, sj, off, ssrc, aggb, N_NODES);

  // ---- fused head-mean + pooling + MLP head ----
  headmean_pool<<<(N_NODES + 15) / 16, 256, 0, stream>>>(aggb, g, N_NODES);
  mlp_kernel<<<1, 128, 0, stream>>>(g, ln_g, ln_b, Wl1, bl1, Wl2, bl2, Wl3, bl3,
                                    out, 1.0f / N_NODES);
}

// Round 14
// 308.827 us; speedup vs baseline: 1.2745x; 1.0076x over previous
//
#include <hip/hip_runtime.h>
#include <math.h>

#define N_NODES 10000
#define N_EDGES 160000
#define N_FEAT  512
#define HEADS   8
#define HID     128

typedef __attribute__((ext_vector_type(8))) short bf16x8;
typedef __attribute__((ext_vector_type(4))) float f32x4;

// ---------------------------------------------------------------------------
// fp32 <-> bf16 helpers
// ---------------------------------------------------------------------------
__device__ inline unsigned short f2bf_rne(float f) {
  unsigned int u = __float_as_uint(f);
  unsigned int r = u + 0x7fffu + ((u >> 16) & 1u);
  return (unsigned short)(r >> 16);
}
__device__ inline float bf2f(unsigned int b) {
  return __uint_as_float(b << 16);
}

// ---------------------------------------------------------------------------
// split body: fp32 [R][K] -> hi/lo bf16 in MFMA-fragment-major layout.
// unit (rb,kq,r) at index (rb*K8+kq)*16+r holds 8 bf16 = A[rb*16+r][kq*8..+8].
// ---------------------------------------------------------------------------
__device__ inline void split_body(const float* __restrict__ in,
                                  unsigned short* __restrict__ hi,
                                  unsigned short* __restrict__ lo,
                                  int R, int K8, int idx) {
  int r = idx & 15;
  int t = idx >> 4;
  int kq = t % K8;
  int rb = t / K8;
  int row = rb * 16 + r;
  float v[8] = {0.f, 0.f, 0.f, 0.f, 0.f, 0.f, 0.f, 0.f};
  if (row < R) {
    const float* p = in + (size_t)row * (K8 * 8) + kq * 8;
    float4 a = *(const float4*)p;
    float4 b = *(const float4*)(p + 4);
    v[0] = a.x; v[1] = a.y; v[2] = a.z; v[3] = a.w;
    v[4] = b.x; v[5] = b.y; v[6] = b.z; v[7] = b.w;
  }
  union { unsigned short u[8]; int4 v4; } H, L;
  #pragma unroll
  for (int e = 0; e < 8; ++e) {
    unsigned short hb_ = f2bf_rne(v[e]);
    H.u[e] = hb_;
    L.u[e] = f2bf_rne(v[e] - bf2f(hb_));
  }
  *(int4*)&hi[(size_t)idx * 8] = H.v4;
  *(int4*)&lo[(size_t)idx * 8] = L.v4;
}

// Combined A + W split (one dispatch): blocks [0,nb1) -> tensor 1, rest -> 2.
__global__ __launch_bounds__(256)
void split_frag2(const float* __restrict__ in1, unsigned short* __restrict__ hi1,
                 unsigned short* __restrict__ lo1, int R1, int K81, int total1,
                 int nb1,
                 const float* __restrict__ in2, unsigned short* __restrict__ hi2,
                 unsigned short* __restrict__ lo2, int R2, int K82, int total2) {
  if ((int)blockIdx.x < nb1) {
    int idx = blockIdx.x * 256 + threadIdx.x;
    if (idx < total1) split_body(in1, hi1, lo1, R1, K81, idx);
  } else {
    int idx = (blockIdx.x - nb1) * 256 + threadIdx.x;
    if (idx < total2) split_body(in2, hi2, lo2, R2, K82, idx);
  }
}

// ---------------------------------------------------------------------------
// LDS-free split-bf16 MFMA GEMM (R8 config — best measured: ~45us, MfmaUtil
// 28%): block = 64 rows x 128 cols (one full head), 2 waves sharing A-frags
// (L1 reuse), single-buffered 16 b128 loads + 48 MFMAs per K-32 per wave.
// Grid 160*8 swizzled: blk%8 == mtile%8 (XCD L2 A-affinity).
// NOTE (R11): smaller tiles raise occupancy but halve per-wave arithmetic
// intensity -> MfmaUtil 13% and 2x slower. NOTE (R10): register double-buffer
// is neutral and doubles VGPR. Do not change tile/buffering.
// ---------------------------------------------------------------------------
__global__ __launch_bounds__(128, 3)
void gemm_frag(const unsigned short* __restrict__ Afh,
               const unsigned short* __restrict__ Afl,
               const unsigned short* __restrict__ Bfh,
               const unsigned short* __restrict__ Bfl,
               const float* __restrict__ avec,
               unsigned short* __restrict__ hb,
               float* __restrict__ si, float* __restrict__ sj,
               int M, int K) {
  __shared__ float rsi[64][2];
  __shared__ float rsj[64][2];
  int tid = threadIdx.x;
  int wave = tid >> 6, lane = tid & 63;
  int r = lane & 15, q = lane >> 4;

  int blk = blockIdx.x;
  int rr = blk & 7, gg = blk >> 3;
  int head = gg & 7;
  int mtile = (gg >> 3) * 8 + rr;     // blk%8 == mtile%8 -> XCD affinity
  int m0 = mtile * 64;
  int wn = wave * 64;
  int K8 = K >> 3;

  const bf16x8* pAh = (const bf16x8*)Afh;
  const bf16x8* pAl = (const bf16x8*)Afl;
  const bf16x8* pBh = (const bf16x8*)Bfh;
  const bf16x8* pBl = (const bf16x8*)Bfl;
  size_t rstep = (size_t)K8 * 16;
  size_t aidx = (size_t)(m0 >> 4) * rstep + (size_t)q * 16 + r;
  size_t bidx = (size_t)(head * 8 + (wn >> 4)) * rstep + (size_t)q * 16 + r;

  f32x4 acc[4][4] = {};

  for (int k0 = 0; k0 < K; k0 += 32, aidx += 64, bidx += 64) {
    bf16x8 ah[4], al[4], bh[4], bl[4];
    #pragma unroll
    for (int i = 0; i < 4; ++i) {
      ah[i] = pAh[aidx + i * rstep];
      al[i] = pAl[aidx + i * rstep];
      bh[i] = pBh[bidx + i * rstep];
      bl[i] = pBl[bidx + i * rstep];
    }
    #pragma unroll
    for (int i = 0; i < 4; ++i)
      #pragma unroll
      for (int j = 0; j < 4; ++j) {
        acc[i][j] = __builtin_amdgcn_mfma_f32_16x16x32_bf16(ah[i], bh[j], acc[i][j], 0, 0, 0);
        acc[i][j] = __builtin_amdgcn_mfma_f32_16x16x32_bf16(ah[i], bl[j], acc[i][j], 0, 0, 0);
        acc[i][j] = __builtin_amdgcn_mfma_f32_16x16x32_bf16(al[i], bh[j], acc[i][j], 0, 0, 0);
      }
  }

  // --- epilogue: C/D layout col = r, row = q*4 + reg (per 16x16 frag) ---
  const float* av = avec + (size_t)head * (2 * HID);
  float aiv[4], ajv[4];
  #pragma unroll
  for (int j = 0; j < 4; ++j) {
    int c = wn + j * 16 + r;
    aiv[j] = av[c];
    ajv[j] = av[HID + c];
  }
  #pragma unroll
  for (int i = 0; i < 4; ++i) {
    #pragma unroll
    for (int reg = 0; reg < 4; ++reg) {
      int lrow = i * 16 + q * 4 + reg;
      int row = m0 + lrow;
      float vsi = 0.f, vsj = 0.f;
      #pragma unroll
      for (int j = 0; j < 4; ++j) {
        float v = acc[i][j][reg];
        vsi = fmaf(v, aiv[j], vsi);
        vsj = fmaf(v, ajv[j], vsj);
        if (row < M)
          hb[((size_t)head * M + row) * HID + wn + j * 16 + r] = f2bf_rne(v);
      }
      #pragma unroll
      for (int o = 8; o >= 1; o >>= 1) {
        vsi += __shfl_xor(vsi, o);
        vsj += __shfl_xor(vsj, o);
      }
      if (r == 0) {
        rsi[lrow][wave] = vsi;
        rsj[lrow][wave] = vsj;
      }
    }
  }
  __syncthreads();
  if (tid < 64) {
    int row = m0 + tid;
    if (row < M) {
      si[(size_t)row * HEADS + head] = rsi[tid][0] + rsi[tid][1];
      sj[(size_t)row * HEADS + head] = rsj[tid][0] + rsj[tid][1];
    }
  }
}

// ---------------------------------------------------------------------------
// CSR build
// ---------------------------------------------------------------------------
__global__ void count_kernel(const int* __restrict__ dst, int* __restrict__ deg, int E) {
  int e = blockIdx.x * blockDim.x + threadIdx.x;
  if (e < E) atomicAdd(&deg[dst[e]], 1);
}

__global__ __launch_bounds__(1024)
void scan_kernel(const int* __restrict__ deg, int* __restrict__ off, int N) {
  __shared__ int sums[1024];
  const int PER = 10;
  int tid = threadIdx.x;
  int base = tid * PER;
  int loc[PER];
  int run = 0;
  #pragma unroll
  for (int j = 0; j < PER; ++j) {
    int v = (base + j < N) ? deg[base + j] : 0;
    run += v;
    loc[j] = run;
  }
  sums[tid] = run;
  __syncthreads();
  for (int o = 1; o < 1024; o <<= 1) {
    int v = (tid >= o) ? sums[tid - o] : 0;
    __syncthreads();
    sums[tid] += v;
    __syncthreads();
  }
  int ex = sums[tid] - run;
  if (tid == 0) off[0] = 0;
  #pragma unroll
  for (int j = 0; j < PER; ++j)
    if (base + j < N) off[base + j + 1] = ex + loc[j];
}

__global__ void fill_kernel(const int* __restrict__ src, const int* __restrict__ dst,
                            const int* __restrict__ off, int* __restrict__ cursor,
                            int* __restrict__ ssrc, int E) {
  int e = blockIdx.x * blockDim.x + threadIdx.x;
  if (e < E) {
    int d = dst[e];
    int p = atomicAdd(&cursor[d], 1);
    ssrc[off[d] + p] = src[e];
  }
}

// ---------------------------------------------------------------------------
// FUSED softmax + aggregation v2: one wave per (dst, head); head=blk&7.
// Phase 1 (64 lanes = 64 edges): one exp per (edge,head); (src,w) written
// ONCE to a per-wave LDS table (R13 post-mortem: per-edge __shfl broadcasts
// = ds_permute on the LDS pipe were slower than agg3's L1 broadcast loads;
// ds_read_b64 of staged pairs is 4 ops/iter vs 8 shfls).
// deg>64 tail: rare recompute loop (Poisson λ=16).
// ---------------------------------------------------------------------------
__global__ __launch_bounds__(512)
void gat_aggregate6(const unsigned short* __restrict__ hb,
                    const float* __restrict__ si, const float* __restrict__ sj,
                    const int* __restrict__ off, const int* __restrict__ ssrc,
                    unsigned short* __restrict__ aggb, int N) {
  __shared__ int2 prs[8][64];   // per-wave (src, w) table, 4 KB
  int head = blockIdx.x & 7;
  int wv = threadIdx.x >> 6;
  int n = (blockIdx.x >> 3) * 8 + wv;   // grid == N/8 blocks: n < N always
  int lane = threadIdx.x & 63;
  int grp = lane >> 4;
  int l = lane & 15;
  const unsigned short* hbase = hb + (size_t)head * N * HID;
  int begin = off[n], end = off[n + 1];
  int deg = end - begin;
  int dmin = deg < 64 ? deg : 64;
  float s_i = si[n * HEADS + head];

  // --- phase 1: per-lane edge score ---
  int src0 = 0;
  float sc0 = -INFINITY;
  if (lane < deg) {
    src0 = ssrc[begin + lane];
    float t = s_i + sj[src0 * HEADS + head];
    sc0 = t > 0.f ? t : 0.01f * t;
  }
  float m = sc0;
  for (int e2 = 64 + lane; e2 < deg; e2 += 64) {     // rare tail max
    int s = ssrc[begin + e2];
    float t = s_i + sj[s * HEADS + head];
    t = t > 0.f ? t : 0.01f * t;
    m = fmaxf(m, t);
  }
  #pragma unroll
  for (int o = 1; o <= 32; o <<= 1) m = fmaxf(m, __shfl_xor(m, o));

  float w0 = (lane < deg) ? expf(sc0 - m) : 0.f;
  float den = w0;
  for (int e2 = 64 + lane; e2 < deg; e2 += 64) {     // rare tail denom
    int s = ssrc[begin + e2];
    float t = s_i + sj[s * HEADS + head];
    t = t > 0.f ? t : 0.01f * t;
    den += expf(t - m);
  }
  #pragma unroll
  for (int o = 1; o <= 32; o <<= 1) den += __shfl_xor(den, o);

  // stage pairs (w=0 for lanes >= deg, src=0 -> safe dummy gather)
  prs[wv][lane] = make_int2(src0, __float_as_int(w0));
  __syncthreads();

  // --- gather phase: 4 groups x 16 lanes, 16 edges per iteration ---
  float a0 = 0.f, a1 = 0.f, a2 = 0.f, a3 = 0.f;
  float a4 = 0.f, a5 = 0.f, a6 = 0.f, a7 = 0.f;

  for (int e0 = 0; e0 < dmin; e0 += 16) {
    float we[4];
    int se[4];
    #pragma unroll
    for (int u = 0; u < 4; ++u) {
      int e = e0 + u * 4 + grp;       // e <= 63 always (e0 <= 48)
      int2 p = prs[wv][e];
      se[u] = p.x;
      we[u] = __int_as_float(p.y);    // already 0 beyond deg
    }
    int4 pv[4];
    #pragma unroll
    for (int u = 0; u < 4; ++u)
      pv[u] = *(const int4*)&hbase[(size_t)se[u] * HID + l * 8];
    #pragma unroll
    for (int u = 0; u < 4; ++u) {
      float wu = we[u];
      int4 p = pv[u];
      a0 = fmaf(wu, bf2f((unsigned)p.x & 0xffffu), a0);
      a1 = fmaf(wu, __uint_as_float((unsigned)p.x & 0xffff0000u), a1);
      a2 = fmaf(wu, bf2f((unsigned)p.y & 0xffffu), a2);
      a3 = fmaf(wu, __uint_as_float((unsigned)p.y & 0xffff0000u), a3);
      a4 = fmaf(wu, bf2f((unsigned)p.z & 0xffffu), a4);
      a5 = fmaf(wu, __uint_as_float((unsigned)p.z & 0xffff0000u), a5);
      a6 = fmaf(wu, bf2f((unsigned)p.w & 0xffffu), a6);
      a7 = fmaf(wu, __uint_as_float((unsigned)p.w & 0xffff0000u), a7);
    }
  }
  // rare tail: deg > 64, recompute weights per group
  for (int e2 = 64; e2 < deg; e2 += 4) {
    int e = e2 + grp;
    bool valid = e < deg;
    int s = ssrc[valid ? begin + e : begin];
    float t = s_i + sj[s * HEADS + head];
    t = t > 0.f ? t : 0.01f * t;
    float wu = valid ? expf(t - m) : 0.f;
    int4 p = *(const int4*)&hbase[(size_t)s * HID + l * 8];
    a0 = fmaf(wu, bf2f((unsigned)p.x & 0xffffu), a0);
    a1 = fmaf(wu, __uint_as_float((unsigned)p.x & 0xffff0000u), a1);
    a2 = fmaf(wu, bf2f((unsigned)p.y & 0xffffu), a2);
    a3 = fmaf(wu, __uint_as_float((unsigned)p.y & 0xffff0000u), a3);
    a4 = fmaf(wu, bf2f((unsigned)p.z & 0xffffu), a4);
    a5 = fmaf(wu, __uint_as_float((unsigned)p.z & 0xffff0000u), a5);
    a6 = fmaf(wu, bf2f((unsigned)p.w & 0xffffu), a6);
    a7 = fmaf(wu, __uint_as_float((unsigned)p.w & 0xffff0000u), a7);
  }

  a0 += __shfl_xor(a0, 16); a1 += __shfl_xor(a1, 16);
  a2 += __shfl_xor(a2, 16); a3 += __shfl_xor(a3, 16);
  a4 += __shfl_xor(a4, 16); a5 += __shfl_xor(a5, 16);
  a6 += __shfl_xor(a6, 16); a7 += __shfl_xor(a7, 16);
  a0 += __shfl_xor(a0, 32); a1 += __shfl_xor(a1, 32);
  a2 += __shfl_xor(a2, 32); a3 += __shfl_xor(a3, 32);
  a4 += __shfl_xor(a4, 32); a5 += __shfl_xor(a5, 32);
  a6 += __shfl_xor(a6, 32); a7 += __shfl_xor(a7, 32);

  if (grp == 0) {
    float inv = den > 0.f ? 1.0f / den : 0.f;
    union { unsigned short u[8]; int4 v4; } P;
    P.u[0] = f2bf_rne(a0 * inv); P.u[1] = f2bf_rne(a1 * inv);
    P.u[2] = f2bf_rne(a2 * inv); P.u[3] = f2bf_rne(a3 * inv);
    P.u[4] = f2bf_rne(a4 * inv); P.u[5] = f2bf_rne(a5 * inv);
    P.u[6] = f2bf_rne(a6 * inv); P.u[7] = f2bf_rne(a7 * inv);
    *(int4*)&aggb[((size_t)head * N + n) * HID + l * 8] = P.v4;
  }
}

// ---------------------------------------------------------------------------
// Head mean + ELU (bf16 aggbuf), writing layer-2 A in frag-major split form,
// FUSED with the W2 split (blocks >= nbHM) — one dispatch.
// ---------------------------------------------------------------------------
__global__ __launch_bounds__(256)
void headmean_frag_w2(const unsigned short* __restrict__ aggb,
                      unsigned short* __restrict__ hiA, unsigned short* __restrict__ loA,
                      int N, int nbHM,
                      const float* __restrict__ W2, unsigned short* __restrict__ hiB,
                      unsigned short* __restrict__ loB, int totalB) {
  if ((int)blockIdx.x >= nbHM) {
    int idx = (blockIdx.x - nbHM) * 256 + threadIdx.x;
    if (idx < totalB) split_body(W2, hiB, loB, HEADS * HID, 16, idx);
    return;
  }
  int idx = blockIdx.x * 256 + threadIdx.x;   // (rb,kq,r), K8=16
  int total = ((N + 15) / 16) * 256;
  if (idx >= total) return;
  int r = idx & 15;
  int kq = (idx >> 4) & 15;
  int rb = idx >> 8;
  int n = rb * 16 + r;
  float s[8] = {0.f, 0.f, 0.f, 0.f, 0.f, 0.f, 0.f, 0.f};
  if (n < N) {
    #pragma unroll
    for (int hh = 0; hh < HEADS; ++hh) {
      int4 pv = *(const int4*)&aggb[((size_t)hh * N + n) * HID + kq * 8];
      s[0] += bf2f((unsigned)pv.x & 0xffffu);
      s[1] += __uint_as_float((unsigned)pv.x & 0xffff0000u);
      s[2] += bf2f((unsigned)pv.y & 0xffffu);
      s[3] += __uint_as_float((unsigned)pv.y & 0xffff0000u);
      s[4] += bf2f((unsigned)pv.z & 0xffffu);
      s[5] += __uint_as_float((unsigned)pv.z & 0xffff0000u);
      s[6] += bf2f((unsigned)pv.w & 0xffffu);
      s[7] += __uint_as_float((unsigned)pv.w & 0xffff0000u);
    }
  }
  union { unsigned short u[8]; int4 v4; } H, L;
  #pragma unroll
  for (int e = 0; e < 8; ++e) {
    float v = s[e] * (1.0f / HEADS);
    v = v > 0.f ? v : (expf(v) - 1.0f);   // ELU
    unsigned short hb_ = f2bf_rne(v);
    H.u[e] = hb_;
    L.u[e] = f2bf_rne(v - bf2f(hb_));
  }
  *(int4*)&hiA[(size_t)idx * 8] = H.v4;
  *(int4*)&loA[(size_t)idx * 8] = L.v4;
}

// ---------------------------------------------------------------------------
// Layer-2 tail: head mean + ELU + graph pooling fused (no emb2 materialized).
// ---------------------------------------------------------------------------
__global__ __launch_bounds__(256)
void headmean_pool(const unsigned short* __restrict__ aggb, float* __restrict__ g,
                   int N) {
  __shared__ float sm[16][128];
  int t = threadIdx.x;
  int nl = t >> 4, dg = t & 15;
  int n = blockIdx.x * 16 + nl;
  float v[8] = {0.f, 0.f, 0.f, 0.f, 0.f, 0.f, 0.f, 0.f};
  if (n < N) {
    #pragma unroll
    for (int hh = 0; hh < HEADS; ++hh) {
      int4 pv = *(const int4*)&aggb[((size_t)hh * N + n) * HID + dg * 8];
      v[0] += bf2f((unsigned)pv.x & 0xffffu);
      v[1] += __uint_as_float((unsigned)pv.x & 0xffff0000u);
      v[2] += bf2f((unsigned)pv.y & 0xffffu);
      v[3] += __uint_as_float((unsigned)pv.y & 0xffff0000u);
      v[4] += bf2f((unsigned)pv.z & 0xffffu);
      v[5] += __uint_as_float((unsigned)pv.z & 0xffff0000u);
      v[6] += bf2f((unsigned)pv.w & 0xffffu);
      v[7] += __uint_as_float((unsigned)pv.w & 0xffff0000u);
    }
    #pragma unroll
    for (int e = 0; e < 8; ++e) {
      float x = v[e] * (1.0f / HEADS);
      v[e] = x > 0.f ? x : (expf(x) - 1.0f);   // ELU
    }
  }
  #pragma unroll
  for (int e = 0; e < 8; ++e) sm[nl][dg * 8 + e] = v[e];
  __syncthreads();
  if (t < 128) {
    float s = 0.f;
    #pragma unroll
    for (int nn = 0; nn < 16; ++nn) s += sm[nn][t];
    atomicAdd(&g[t], s);
  }
}

// ---------------------------------------------------------------------------
// LayerNorm + MLP head
// ---------------------------------------------------------------------------
__global__ __launch_bounds__(128)
void mlp_kernel(const float* __restrict__ g, const float* __restrict__ ln_g,
                const float* __restrict__ ln_b, const float* __restrict__ Wl1,
                const float* __restrict__ bl1, const float* __restrict__ Wl2,
                const float* __restrict__ bl2, const float* __restrict__ Wl3,
                const float* __restrict__ bl3, float* __restrict__ out, float invN) {
  __shared__ float red[128];
  __shared__ float gn[128];
  __shared__ float x1[64];
  __shared__ float x2[16];
  int t = threadIdx.x;
  float gg = g[t] * invN;
  red[t] = gg;
  __syncthreads();
  for (int o = 64; o > 0; o >>= 1) {
    if (t < o) red[t] += red[t + o];
    __syncthreads();
  }
  float mu = red[0] * (1.0f / HID);
  __syncthreads();
  float dv = gg - mu;
  red[t] = dv * dv;
  __syncthreads();
  for (int o = 64; o > 0; o >>= 1) {
    if (t < o) red[t] += red[t + o];
    __syncthreads();
  }
  float var = red[0] * (1.0f / HID);
  gn[t] = dv / sqrtf(var + 1e-5f) * ln_g[t] + ln_b[t];
  __syncthreads();
  if (t < 64) {
    float s = bl1[t];
    for (int k = 0; k < 128; ++k) s += Wl1[t * 128 + k] * gn[k];
    x1[t] = s > 0.f ? s : 0.01f * s;
  }
  __syncthreads();
  if (t < 16) {
    float s = bl2[t];
    for (int k = 0; k < 64; ++k) s += Wl2[t * 64 + k] * x1[k];
    x2[t] = s > 0.f ? s : 0.01f * s;
  }
  __syncthreads();
  if (t < 16) {
    float s = bl3[t];
    for (int k = 0; k < 16; ++k) s += Wl3[t * 16 + k] * x2[k];
    out[t] = s > 0.f ? s : 0.f;
  }
}

// ---------------------------------------------------------------------------
extern "C" void kernel_launch(void* const* d_in, const int* in_sizes, int n_in,
                              void* d_out, int out_size, void* d_ws, size_t ws_size,
                              hipStream_t stream) {
  const float* x    = (const float*)d_in[0];
  const int*   esrc = (const int*)d_in[1];
  const int*   edst = (const int*)d_in[2];
  const float* W1   = (const float*)d_in[3];
  const float* a1   = (const float*)d_in[4];
  const float* W2   = (const float*)d_in[5];
  const float* a2   = (const float*)d_in[6];
  const float* ln_g = (const float*)d_in[7];
  const float* ln_b = (const float*)d_in[8];
  const float* Wl1  = (const float*)d_in[9];
  const float* bl1  = (const float*)d_in[10];
  const float* Wl2  = (const float*)d_in[11];
  const float* bl2  = (const float*)d_in[12];
  const float* Wl3  = (const float*)d_in[13];
  const float* bl3  = (const float*)d_in[14];
  float* out = (float*)d_out;

  const int RBPAD = 640;  // row-blocks padded (10240 rows) for in-bounds frags

  // workspace carve-up (g, deg, cur contiguous -> one memset)
  unsigned short* aggb = (unsigned short*)d_ws;                 // 20.5 MB
  float* si   = (float*)(aggb + (size_t)N_NODES * HEADS * HID); // 80,000
  float* sj   = si + N_NODES * HEADS;                           // 80,000
  float* g    = sj + N_NODES * HEADS;                           // 128
  int*   deg  = (int*)(g + 128);                                // 10,000
  int*   cur  = deg + N_NODES;                                  // 10,000
  int*   off  = cur + N_NODES;                                  // 10,001 -> pad 10,004
  int*   ssrc = off + 10004;                                    // 160,000
  unsigned short* Afh = (unsigned short*)(ssrc + N_EDGES);      // 640*64*128 us
  unsigned short* Afl = Afh + (size_t)RBPAD * 64 * 128;
  unsigned short* Bfh = Afl + (size_t)RBPAD * 64 * 128;
  unsigned short* Bfl = Bfh + (size_t)64 * 64 * 128;
  unsigned short* hb  = Bfl + (size_t)64 * 64 * 128;            // 20.5 MB

  // zero g + deg + cur in ONE memset (contiguous)
  hipMemsetAsync(g, 0, 128 * sizeof(float) + 2 * N_NODES * sizeof(int), stream);
  count_kernel<<<(N_EDGES + 255) / 256, 256, 0, stream>>>(edst, deg, N_EDGES);
  scan_kernel<<<1, 1024, 0, stream>>>(deg, off, N_NODES);
  fill_kernel<<<(N_EDGES + 255) / 256, 256, 0, stream>>>(esrc, edst, off, cur, ssrc, N_EDGES);

  int gemmGrid = 160 * HEADS;                 // 1280 blocks of 128 threads
  int aggGrid = (N_NODES / 8) * 8;            // 10000 blocks (N % 8 == 0)

  // ---- Layer 1 ----
  {
    int totalA = RBPAD * 64 * 16;             // K8=64
    int nbA = (totalA + 255) / 256;           // 2560
    int totalB = 64 * 64 * 16;                // 1024 rows, K8=64
    int nbB = (totalB + 255) / 256;           // 256
    split_frag2<<<nbA + nbB, 256, 0, stream>>>(x, Afh, Afl, N_NODES, 64, totalA, nbA,
                                               W1, Bfh, Bfl, HEADS * HID, 64, totalB);
    gemm_frag<<<gemmGrid, 128, 0, stream>>>(Afh, Afl, Bfh, Bfl, a1, hb,
                                            si, sj, N_NODES, N_FEAT);
  }
  gat_aggregate6<<<aggGrid, 512, 0, stream>>>(hb, si, sj, off, ssrc, aggb, N_NODES);
  {
    int nbHM = ((N_NODES + 15) / 16 * 256 + 255) / 256;   // 625
    int totalB = 64 * 16 * 16;                            // W2: 1024 rows, K8=16
    int nbB = (totalB + 255) / 256;                       // 64
    headmean_frag_w2<<<nbHM + nbB, 256, 0, stream>>>(aggb, Afh, Afl, N_NODES, nbHM,
                                                     W2, Bfh, Bfl, totalB);
  }

  // ---- Layer 2 ----
  gemm_frag<<<gemmGrid, 128, 0, stream>>>(Afh, Afl, Bfh, Bfl, a2, hb,
                                          si, sj, N_NODES, HID);
  gat_aggregate6<<<aggGrid, 512, 0, stream>>>(hb, si, sj, off, ssrc, aggb, N_NODES);

  // ---- fused head-mean + pooling + MLP head ----
  headmean_pool<<<(N_NODES + 15) / 16, 256, 0, stream>>>(aggb, g, N_NODES);
  mlp_kernel<<<1, 128, 0, stream>>>(g, ln_g, ln_b, Wl1, bl1, Wl2, bl2, Wl3, bl3,
                                    out, 1.0f / N_NODES);
}

// Round 15
// 302.556 us; speedup vs baseline: 1.3009x; 1.0207x over previous
//
#include <hip/hip_runtime.h>
#include <math.h>

#define N_NODES 10000
#define N_EDGES 160000
#define N_FEAT  512
#define HEADS   8
#define HID     128

typedef __attribute__((ext_vector_type(8))) short bf16x8;
typedef __attribute__((ext_vector_type(4))) float f32x4;
typedef __attribute__((ext_vector_type(2))) float v2f;

// ---------------------------------------------------------------------------
// fp32 <-> bf16 helpers
// ---------------------------------------------------------------------------
__device__ inline unsigned short f2bf_rne(float f) {
  unsigned int u = __float_as_uint(f);
  unsigned int r = u + 0x7fffu + ((u >> 16) & 1u);
  return (unsigned short)(r >> 16);
}
__device__ inline float bf2f(unsigned int b) {
  return __uint_as_float(b << 16);
}

// ---------------------------------------------------------------------------
// split body: fp32 [R][K] -> hi/lo bf16 in MFMA-fragment-major layout.
// ---------------------------------------------------------------------------
__device__ inline void split_body(const float* __restrict__ in,
                                  unsigned short* __restrict__ hi,
                                  unsigned short* __restrict__ lo,
                                  int R, int K8, int idx) {
  int r = idx & 15;
  int t = idx >> 4;
  int kq = t % K8;
  int rb = t / K8;
  int row = rb * 16 + r;
  float v[8] = {0.f, 0.f, 0.f, 0.f, 0.f, 0.f, 0.f, 0.f};
  if (row < R) {
    const float* p = in + (size_t)row * (K8 * 8) + kq * 8;
    float4 a = *(const float4*)p;
    float4 b = *(const float4*)(p + 4);
    v[0] = a.x; v[1] = a.y; v[2] = a.z; v[3] = a.w;
    v[4] = b.x; v[5] = b.y; v[6] = b.z; v[7] = b.w;
  }
  union { unsigned short u[8]; int4 v4; } H, L;
  #pragma unroll
  for (int e = 0; e < 8; ++e) {
    unsigned short hb_ = f2bf_rne(v[e]);
    H.u[e] = hb_;
    L.u[e] = f2bf_rne(v[e] - bf2f(hb_));
  }
  *(int4*)&hi[(size_t)idx * 8] = H.v4;
  *(int4*)&lo[(size_t)idx * 8] = L.v4;
}

// Combined A + W split (one dispatch): blocks [0,nb1) -> tensor 1, rest -> 2.
__global__ __launch_bounds__(256)
void split_frag2(const float* __restrict__ in1, unsigned short* __restrict__ hi1,
                 unsigned short* __restrict__ lo1, int R1, int K81, int total1,
                 int nb1,
                 const float* __restrict__ in2, unsigned short* __restrict__ hi2,
                 unsigned short* __restrict__ lo2, int R2, int K82, int total2) {
  if ((int)blockIdx.x < nb1) {
    int idx = blockIdx.x * 256 + threadIdx.x;
    if (idx < total1) split_body(in1, hi1, lo1, R1, K81, idx);
  } else {
    int idx = (blockIdx.x - nb1) * 256 + threadIdx.x;
    if (idx < total2) split_body(in2, hi2, lo2, R2, K82, idx);
  }
}

// ---------------------------------------------------------------------------
// LDS-free split-bf16 MFMA GEMM (R8 config — best measured: ~45us, MfmaUtil
// 28%). NOTE (R11): smaller tiles raise occupancy but halve per-wave
// arithmetic intensity -> 2x slower. NOTE (R10): register double-buffer is
// neutral. Frozen.
// ---------------------------------------------------------------------------
__global__ __launch_bounds__(128, 3)
void gemm_frag(const unsigned short* __restrict__ Afh,
               const unsigned short* __restrict__ Afl,
               const unsigned short* __restrict__ Bfh,
               const unsigned short* __restrict__ Bfl,
               const float* __restrict__ avec,
               unsigned short* __restrict__ hb,
               float* __restrict__ si, float* __restrict__ sj,
               int M, int K) {
  __shared__ float rsi[64][2];
  __shared__ float rsj[64][2];
  int tid = threadIdx.x;
  int wave = tid >> 6, lane = tid & 63;
  int r = lane & 15, q = lane >> 4;

  int blk = blockIdx.x;
  int rr = blk & 7, gg = blk >> 3;
  int head = gg & 7;
  int mtile = (gg >> 3) * 8 + rr;     // blk%8 == mtile%8 -> XCD affinity
  int m0 = mtile * 64;
  int wn = wave * 64;
  int K8 = K >> 3;

  const bf16x8* pAh = (const bf16x8*)Afh;
  const bf16x8* pAl = (const bf16x8*)Afl;
  const bf16x8* pBh = (const bf16x8*)Bfh;
  const bf16x8* pBl = (const bf16x8*)Bfl;
  size_t rstep = (size_t)K8 * 16;
  size_t aidx = (size_t)(m0 >> 4) * rstep + (size_t)q * 16 + r;
  size_t bidx = (size_t)(head * 8 + (wn >> 4)) * rstep + (size_t)q * 16 + r;

  f32x4 acc[4][4] = {};

  for (int k0 = 0; k0 < K; k0 += 32, aidx += 64, bidx += 64) {
    bf16x8 ah[4], al[4], bh[4], bl[4];
    #pragma unroll
    for (int i = 0; i < 4; ++i) {
      ah[i] = pAh[aidx + i * rstep];
      al[i] = pAl[aidx + i * rstep];
      bh[i] = pBh[bidx + i * rstep];
      bl[i] = pBl[bidx + i * rstep];
    }
    #pragma unroll
    for (int i = 0; i < 4; ++i)
      #pragma unroll
      for (int j = 0; j < 4; ++j) {
        acc[i][j] = __builtin_amdgcn_mfma_f32_16x16x32_bf16(ah[i], bh[j], acc[i][j], 0, 0, 0);
        acc[i][j] = __builtin_amdgcn_mfma_f32_16x16x32_bf16(ah[i], bl[j], acc[i][j], 0, 0, 0);
        acc[i][j] = __builtin_amdgcn_mfma_f32_16x16x32_bf16(al[i], bh[j], acc[i][j], 0, 0, 0);
      }
  }

  // --- epilogue: C/D layout col = r, row = q*4 + reg (per 16x16 frag) ---
  const float* av = avec + (size_t)head * (2 * HID);
  float aiv[4], ajv[4];
  #pragma unroll
  for (int j = 0; j < 4; ++j) {
    int c = wn + j * 16 + r;
    aiv[j] = av[c];
    ajv[j] = av[HID + c];
  }
  #pragma unroll
  for (int i = 0; i < 4; ++i) {
    #pragma unroll
    for (int reg = 0; reg < 4; ++reg) {
      int lrow = i * 16 + q * 4 + reg;
      int row = m0 + lrow;
      float vsi = 0.f, vsj = 0.f;
      #pragma unroll
      for (int j = 0; j < 4; ++j) {
        float v = acc[i][j][reg];
        vsi = fmaf(v, aiv[j], vsi);
        vsj = fmaf(v, ajv[j], vsj);
        if (row < M)
          hb[((size_t)head * M + row) * HID + wn + j * 16 + r] = f2bf_rne(v);
      }
      #pragma unroll
      for (int o = 8; o >= 1; o >>= 1) {
        vsi += __shfl_xor(vsi, o);
        vsj += __shfl_xor(vsj, o);
      }
      if (r == 0) {
        rsi[lrow][wave] = vsi;
        rsj[lrow][wave] = vsj;
      }
    }
  }
  __syncthreads();
  if (tid < 64) {
    int row = m0 + tid;
    if (row < M) {
      si[(size_t)row * HEADS + head] = rsi[tid][0] + rsi[tid][1];
      sj[(size_t)row * HEADS + head] = rsj[tid][0] + rsj[tid][1];
    }
  }
}

// ---------------------------------------------------------------------------
// CSR build
// ---------------------------------------------------------------------------
__global__ void count_kernel(const int* __restrict__ dst, int* __restrict__ deg, int E) {
  int e = blockIdx.x * blockDim.x + threadIdx.x;
  if (e < E) atomicAdd(&deg[dst[e]], 1);
}

__global__ __launch_bounds__(1024)
void scan_kernel(const int* __restrict__ deg, int* __restrict__ off, int N) {
  __shared__ int sums[1024];
  const int PER = 10;
  int tid = threadIdx.x;
  int base = tid * PER;
  int loc[PER];
  int run = 0;
  #pragma unroll
  for (int j = 0; j < PER; ++j) {
    int v = (base + j < N) ? deg[base + j] : 0;
    run += v;
    loc[j] = run;
  }
  sums[tid] = run;
  __syncthreads();
  for (int o = 1; o < 1024; o <<= 1) {
    int v = (tid >= o) ? sums[tid - o] : 0;
    __syncthreads();
    sums[tid] += v;
    __syncthreads();
  }
  int ex = sums[tid] - run;
  if (tid == 0) off[0] = 0;
  #pragma unroll
  for (int j = 0; j < PER; ++j)
    if (base + j < N) off[base + j + 1] = ex + loc[j];
}

__global__ void fill_kernel(const int* __restrict__ src, const int* __restrict__ dst,
                            const int* __restrict__ off, int* __restrict__ cursor,
                            int* __restrict__ ssrc, int E) {
  int e = blockIdx.x * blockDim.x + threadIdx.x;
  if (e < E) {
    int d = dst[e];
    int p = atomicAdd(&cursor[d], 1);
    ssrc[off[d] + p] = src[e];
  }
}

// ---------------------------------------------------------------------------
// FUSED softmax + aggregation v3: one wave per (dst, head); head=blk&7.
// Phase 1 (64 lanes = 64 edges): one exp per (edge,head); (src,w) staged in
// a per-WAVE LDS table. No block barrier (wave-synchronous LDS: each wave
// reads only its own row; lgkmcnt fence stops compiler reorder) — avoids all
// 8 waves stalling on the block's max degree. Gather loop accumulates in
// float2 ext-vectors -> v_pk_fma_f32 (R14 post-mortem: gather is VALU-issue
// bound; packed FMA cuts per-2-dim cost 4->3 VALU ops).
// ---------------------------------------------------------------------------
__global__ __launch_bounds__(512)
void gat_aggregate7(const unsigned short* __restrict__ hb,
                    const float* __restrict__ si, const float* __restrict__ sj,
                    const int* __restrict__ off, const int* __restrict__ ssrc,
                    unsigned short* __restrict__ aggb, int N) {
  __shared__ int2 prs[8][64];   // per-wave (src, w) table
  int head = blockIdx.x & 7;
  int wv = threadIdx.x >> 6;
  int n = (blockIdx.x >> 3) * 8 + wv;   // grid == N/8 blocks: n < N always
  int lane = threadIdx.x & 63;
  int grp = lane >> 4;
  int l = lane & 15;
  const unsigned short* hbase = hb + (size_t)head * N * HID;
  int begin = off[n], end = off[n + 1];
  int deg = end - begin;
  int dmin = deg < 64 ? deg : 64;
  float s_i = si[n * HEADS + head];

  // --- phase 1: per-lane edge score ---
  int src0 = 0;
  float sc0 = -INFINITY;
  if (lane < deg) {
    src0 = ssrc[begin + lane];
    float t = s_i + sj[src0 * HEADS + head];
    sc0 = t > 0.f ? t : 0.01f * t;
  }
  float m = sc0;
  for (int e2 = 64 + lane; e2 < deg; e2 += 64) {     // rare tail max
    int s = ssrc[begin + e2];
    float t = s_i + sj[s * HEADS + head];
    t = t > 0.f ? t : 0.01f * t;
    m = fmaxf(m, t);
  }
  #pragma unroll
  for (int o = 1; o <= 32; o <<= 1) m = fmaxf(m, __shfl_xor(m, o));

  float w0 = (lane < deg) ? expf(sc0 - m) : 0.f;
  float den = w0;
  for (int e2 = 64 + lane; e2 < deg; e2 += 64) {     // rare tail denom
    int s = ssrc[begin + e2];
    float t = s_i + sj[s * HEADS + head];
    t = t > 0.f ? t : 0.01f * t;
    den += expf(t - m);
  }
  #pragma unroll
  for (int o = 1; o <= 32; o <<= 1) den += __shfl_xor(den, o);

  // stage pairs (w=0 for lanes >= deg; src=0 -> safe dummy gather)
  prs[wv][lane] = make_int2(src0, __float_as_int(w0));
  // wave-synchronous LDS: ensure writes land + block compiler reorder.
  __asm__ volatile("s_waitcnt lgkmcnt(0)" ::: "memory");

  // --- gather phase: 4 groups x 16 lanes, 16 edges per iteration ---
  v2f a01 = {0.f, 0.f}, a23 = {0.f, 0.f}, a45 = {0.f, 0.f}, a67 = {0.f, 0.f};

  for (int e0 = 0; e0 < dmin; e0 += 16) {
    float we[4];
    int se[4];
    #pragma unroll
    for (int u = 0; u < 4; ++u) {
      int e = e0 + u * 4 + grp;       // e <= 63 always (e0 <= 48)
      int2 p = prs[wv][e];
      se[u] = p.x;
      we[u] = __int_as_float(p.y);    // already 0 beyond deg
    }
    int4 pv[4];
    #pragma unroll
    for (int u = 0; u < 4; ++u)
      pv[u] = *(const int4*)&hbase[(size_t)se[u] * HID + l * 8];
    #pragma unroll
    for (int u = 0; u < 4; ++u) {
      v2f w2 = {we[u], we[u]};
      int4 p = pv[u];
      v2f t0 = {bf2f((unsigned)p.x & 0xffffu), __uint_as_float((unsigned)p.x & 0xffff0000u)};
      v2f t1 = {bf2f((unsigned)p.y & 0xffffu), __uint_as_float((unsigned)p.y & 0xffff0000u)};
      v2f t2 = {bf2f((unsigned)p.z & 0xffffu), __uint_as_float((unsigned)p.z & 0xffff0000u)};
      v2f t3 = {bf2f((unsigned)p.w & 0xffffu), __uint_as_float((unsigned)p.w & 0xffff0000u)};
      a01 += w2 * t0;                 // v_pk_fma_f32
      a23 += w2 * t1;
      a45 += w2 * t2;
      a67 += w2 * t3;
    }
  }
  // rare tail: deg > 64, recompute weights per group
  for (int e2 = 64; e2 < deg; e2 += 4) {
    int e = e2 + grp;
    bool valid = e < deg;
    int s = ssrc[valid ? begin + e : begin];
    float t = s_i + sj[s * HEADS + head];
    t = t > 0.f ? t : 0.01f * t;
    float wu = valid ? expf(t - m) : 0.f;
    v2f w2 = {wu, wu};
    int4 p = *(const int4*)&hbase[(size_t)s * HID + l * 8];
    v2f t0 = {bf2f((unsigned)p.x & 0xffffu), __uint_as_float((unsigned)p.x & 0xffff0000u)};
    v2f t1 = {bf2f((unsigned)p.y & 0xffffu), __uint_as_float((unsigned)p.y & 0xffff0000u)};
    v2f t2 = {bf2f((unsigned)p.z & 0xffffu), __uint_as_float((unsigned)p.z & 0xffff0000u)};
    v2f t3 = {bf2f((unsigned)p.w & 0xffffu), __uint_as_float((unsigned)p.w & 0xffff0000u)};
    a01 += w2 * t0; a23 += w2 * t1; a45 += w2 * t2; a67 += w2 * t3;
  }

  // reduce across the 4 edge groups
  #pragma unroll
  for (int o = 16; o <= 32; o <<= 1) {
    a01.x += __shfl_xor(a01.x, o); a01.y += __shfl_xor(a01.y, o);
    a23.x += __shfl_xor(a23.x, o); a23.y += __shfl_xor(a23.y, o);
    a45.x += __shfl_xor(a45.x, o); a45.y += __shfl_xor(a45.y, o);
    a67.x += __shfl_xor(a67.x, o); a67.y += __shfl_xor(a67.y, o);
  }

  if (grp == 0) {
    float inv = den > 0.f ? 1.0f / den : 0.f;
    union { unsigned short u[8]; int4 v4; } P;
    P.u[0] = f2bf_rne(a01.x * inv); P.u[1] = f2bf_rne(a01.y * inv);
    P.u[2] = f2bf_rne(a23.x * inv); P.u[3] = f2bf_rne(a23.y * inv);
    P.u[4] = f2bf_rne(a45.x * inv); P.u[5] = f2bf_rne(a45.y * inv);
    P.u[6] = f2bf_rne(a67.x * inv); P.u[7] = f2bf_rne(a67.y * inv);
    *(int4*)&aggb[((size_t)head * N + n) * HID + l * 8] = P.v4;
  }
}

// ---------------------------------------------------------------------------
// Head mean + ELU (bf16 aggbuf), writing layer-2 A in frag-major split form,
// FUSED with the W2 split (blocks >= nbHM).
// ---------------------------------------------------------------------------
__global__ __launch_bounds__(256)
void headmean_frag_w2(const unsigned short* __restrict__ aggb,
                      unsigned short* __restrict__ hiA, unsigned short* __restrict__ loA,
                      int N, int nbHM,
                      const float* __restrict__ W2, unsigned short* __restrict__ hiB,
                      unsigned short* __restrict__ loB, int totalB) {
  if ((int)blockIdx.x >= nbHM) {
    int idx = (blockIdx.x - nbHM) * 256 + threadIdx.x;
    if (idx < totalB) split_body(W2, hiB, loB, HEADS * HID, 16, idx);
    return;
  }
  int idx = blockIdx.x * 256 + threadIdx.x;   // (rb,kq,r), K8=16
  int total = ((N + 15) / 16) * 256;
  if (idx >= total) return;
  int r = idx & 15;
  int kq = (idx >> 4) & 15;
  int rb = idx >> 8;
  int n = rb * 16 + r;
  float s[8] = {0.f, 0.f, 0.f, 0.f, 0.f, 0.f, 0.f, 0.f};
  if (n < N) {
    #pragma unroll
    for (int hh = 0; hh < HEADS; ++hh) {
      int4 pv = *(const int4*)&aggb[((size_t)hh * N + n) * HID + kq * 8];
      s[0] += bf2f((unsigned)pv.x & 0xffffu);
      s[1] += __uint_as_float((unsigned)pv.x & 0xffff0000u);
      s[2] += bf2f((unsigned)pv.y & 0xffffu);
      s[3] += __uint_as_float((unsigned)pv.y & 0xffff0000u);
      s[4] += bf2f((unsigned)pv.z & 0xffffu);
      s[5] += __uint_as_float((unsigned)pv.z & 0xffff0000u);
      s[6] += bf2f((unsigned)pv.w & 0xffffu);
      s[7] += __uint_as_float((unsigned)pv.w & 0xffff0000u);
    }
  }
  union { unsigned short u[8]; int4 v4; } H, L;
  #pragma unroll
  for (int e = 0; e < 8; ++e) {
    float v = s[e] * (1.0f / HEADS);
    v = v > 0.f ? v : (expf(v) - 1.0f);   // ELU
    unsigned short hb_ = f2bf_rne(v);
    H.u[e] = hb_;
    L.u[e] = f2bf_rne(v - bf2f(hb_));
  }
  *(int4*)&hiA[(size_t)idx * 8] = H.v4;
  *(int4*)&loA[(size_t)idx * 8] = L.v4;
}

// ---------------------------------------------------------------------------
// Layer-2 tail: head mean + ELU + graph pooling fused (no emb2 materialized).
// ---------------------------------------------------------------------------
__global__ __launch_bounds__(256)
void headmean_pool(const unsigned short* __restrict__ aggb, float* __restrict__ g,
                   int N) {
  __shared__ float sm[16][128];
  int t = threadIdx.x;
  int nl = t >> 4, dg = t & 15;
  int n = blockIdx.x * 16 + nl;
  float v[8] = {0.f, 0.f, 0.f, 0.f, 0.f, 0.f, 0.f, 0.f};
  if (n < N) {
    #pragma unroll
    for (int hh = 0; hh < HEADS; ++hh) {
      int4 pv = *(const int4*)&aggb[((size_t)hh * N + n) * HID + dg * 8];
      v[0] += bf2f((unsigned)pv.x & 0xffffu);
      v[1] += __uint_as_float((unsigned)pv.x & 0xffff0000u);
      v[2] += bf2f((unsigned)pv.y & 0xffffu);
      v[3] += __uint_as_float((unsigned)pv.y & 0xffff0000u);
      v[4] += bf2f((unsigned)pv.z & 0xffffu);
      v[5] += __uint_as_float((unsigned)pv.z & 0xffff0000u);
      v[6] += bf2f((unsigned)pv.w & 0xffffu);
      v[7] += __uint_as_float((unsigned)pv.w & 0xffff0000u);
    }
    #pragma unroll
    for (int e = 0; e < 8; ++e) {
      float x = v[e] * (1.0f / HEADS);
      v[e] = x > 0.f ? x : (expf(x) - 1.0f);   // ELU
    }
  }
  #pragma unroll
  for (int e = 0; e < 8; ++e) sm[nl][dg * 8 + e] = v[e];
  __syncthreads();
  if (t < 128) {
    float s = 0.f;
    #pragma unroll
    for (int nn = 0; nn < 16; ++nn) s += sm[nn][t];
    atomicAdd(&g[t], s);
  }
}

// ---------------------------------------------------------------------------
// LayerNorm + MLP head
// ---------------------------------------------------------------------------
__global__ __launch_bounds__(128)
void mlp_kernel(const float* __restrict__ g, const float* __restrict__ ln_g,
                const float* __restrict__ ln_b, const float* __restrict__ Wl1,
                const float* __restrict__ bl1, const float* __restrict__ Wl2,
                const float* __restrict__ bl2, const float* __restrict__ Wl3,
                const float* __restrict__ bl3, float* __restrict__ out, float invN) {
  __shared__ float red[128];
  __shared__ float gn[128];
  __shared__ float x1[64];
  __shared__ float x2[16];
  int t = threadIdx.x;
  float gg = g[t] * invN;
  red[t] = gg;
  __syncthreads();
  for (int o = 64; o > 0; o >>= 1) {
    if (t < o) red[t] += red[t + o];
    __syncthreads();
  }
  float mu = red[0] * (1.0f / HID);
  __syncthreads();
  float dv = gg - mu;
  red[t] = dv * dv;
  __syncthreads();
  for (int o = 64; o > 0; o >>= 1) {
    if (t < o) red[t] += red[t + o];
    __syncthreads();
  }
  float var = red[0] * (1.0f / HID);
  gn[t] = dv / sqrtf(var + 1e-5f) * ln_g[t] + ln_b[t];
  __syncthreads();
  if (t < 64) {
    float s = bl1[t];
    for (int k = 0; k < 128; ++k) s += Wl1[t * 128 + k] * gn[k];
    x1[t] = s > 0.f ? s : 0.01f * s;
  }
  __syncthreads();
  if (t < 16) {
    float s = bl2[t];
    for (int k = 0; k < 64; ++k) s += Wl2[t * 64 + k] * x1[k];
    x2[t] = s > 0.f ? s : 0.01f * s;
  }
  __syncthreads();
  if (t < 16) {
    float s = bl3[t];
    for (int k = 0; k < 16; ++k) s += Wl3[t * 16 + k] * x2[k];
    out[t] = s > 0.f ? s : 0.f;
  }
}

// ---------------------------------------------------------------------------
extern "C" void kernel_launch(void* const* d_in, const int* in_sizes, int n_in,
                              void* d_out, int out_size, void* d_ws, size_t ws_size,
                              hipStream_t stream) {
  const float* x    = (const float*)d_in[0];
  const int*   esrc = (const int*)d_in[1];
  const int*   edst = (const int*)d_in[2];
  const float* W1   = (const float*)d_in[3];
  const float* a1   = (const float*)d_in[4];
  const float* W2   = (const float*)d_in[5];
  const float* a2   = (const float*)d_in[6];
  const float* ln_g = (const float*)d_in[7];
  const float* ln_b = (const float*)d_in[8];
  const float* Wl1  = (const float*)d_in[9];
  const float* bl1  = (const float*)d_in[10];
  const float* Wl2  = (const float*)d_in[11];
  const float* bl2  = (const float*)d_in[12];
  const float* Wl3  = (const float*)d_in[13];
  const float* bl3  = (const float*)d_in[14];
  float* out = (float*)d_out;

  const int RBPAD = 640;  // row-blocks padded (10240 rows) for in-bounds frags

  // workspace carve-up (g, deg, cur contiguous -> one memset)
  unsigned short* aggb = (unsigned short*)d_ws;                 // 20.5 MB
  float* si   = (float*)(aggb + (size_t)N_NODES * HEADS * HID); // 80,000
  float* sj   = si + N_NODES * HEADS;                           // 80,000
  float* g    = sj + N_NODES * HEADS;                           // 128
  int*   deg  = (int*)(g + 128);                                // 10,000
  int*   cur  = deg + N_NODES;                                  // 10,000
  int*   off  = cur + N_NODES;                                  // 10,001 -> pad 10,004
  int*   ssrc = off + 10004;                                    // 160,000
  unsigned short* Afh = (unsigned short*)(ssrc + N_EDGES);      // 640*64*128 us
  unsigned short* Afl = Afh + (size_t)RBPAD * 64 * 128;
  unsigned short* Bfh = Afl + (size_t)RBPAD * 64 * 128;
  unsigned short* Bfl = Bfh + (size_t)64 * 64 * 128;
  unsigned short* hb  = Bfl + (size_t)64 * 64 * 128;            // 20.5 MB

  // zero g + deg + cur in ONE memset (contiguous)
  hipMemsetAsync(g, 0, 128 * sizeof(float) + 2 * N_NODES * sizeof(int), stream);
  count_kernel<<<(N_EDGES + 255) / 256, 256, 0, stream>>>(edst, deg, N_EDGES);
  scan_kernel<<<1, 1024, 0, stream>>>(deg, off, N_NODES);
  fill_kernel<<<(N_EDGES + 255) / 256, 256, 0, stream>>>(esrc, edst, off, cur, ssrc, N_EDGES);

  int gemmGrid = 160 * HEADS;                 // 1280 blocks of 128 threads
  int aggGrid = (N_NODES / 8) * 8;            // 10000 blocks (N % 8 == 0)

  // ---- Layer 1 ----
  {
    int totalA = RBPAD * 64 * 16;             // K8=64
    int nbA = (totalA + 255) / 256;           // 2560
    int totalB = 64 * 64 * 16;                // 1024 rows, K8=64
    int nbB = (totalB + 255) / 256;           // 256
    split_frag2<<<nbA + nbB, 256, 0, stream>>>(x, Afh, Afl, N_NODES, 64, totalA, nbA,
                                               W1, Bfh, Bfl, HEADS * HID, 64, totalB);
    gemm_frag<<<gemmGrid, 128, 0, stream>>>(Afh, Afl, Bfh, Bfl, a1, hb,
                                            si, sj, N_NODES, N_FEAT);
  }
  gat_aggregate7<<<aggGrid, 512, 0, stream>>>(hb, si, sj, off, ssrc, aggb, N_NODES);
  {
    int nbHM = ((N_NODES + 15) / 16 * 256 + 255) / 256;   // 625
    int totalB = 64 * 16 * 16;                            // W2: 1024 rows, K8=16
    int nbB = (totalB + 255) / 256;                       // 64
    headmean_frag_w2<<<nbHM + nbB, 256, 0, stream>>>(aggb, Afh, Afl, N_NODES, nbHM,
                                                     W2, Bfh, Bfl, totalB);
  }

  // ---- Layer 2 ----
  gemm_frag<<<gemmGrid, 128, 0, stream>>>(Afh, Afl, Bfh, Bfl, a2, hb,
                                          si, sj, N_NODES, HID);
  gat_aggregate7<<<aggGrid, 512, 0, stream>>>(hb, si, sj, off, ssrc, aggb, N_NODES);

  // ---- fused head-mean + pooling + MLP head ----
  headmean_pool<<<(N_NODES + 15) / 16, 256, 0, stream>>>(aggb, g, N_NODES);
  mlp_kernel<<<1, 128, 0, stream>>>(g, ln_g, ln_b, Wl1, bl1, Wl2, bl2, Wl3, bl3,
                                    out, 1.0f / N_NODES);
}

// Round 16
// 299.621 us; speedup vs baseline: 1.3137x; 1.0098x over previous
//
#include <hip/hip_runtime.h>
#include <math.h>

#define N_NODES 10000
#define N_EDGES 160000
#define N_FEAT  512
#define HEADS   8
#define HID     128

typedef __attribute__((ext_vector_type(8))) short bf16x8;
typedef __attribute__((ext_vector_type(4))) float f32x4;
typedef __attribute__((ext_vector_type(2))) float v2f;

// ---------------------------------------------------------------------------
// fp32 <-> bf16 helpers
// ---------------------------------------------------------------------------
__device__ inline unsigned short f2bf_rne(float f) {
  unsigned int u = __float_as_uint(f);
  unsigned int r = u + 0x7fffu + ((u >> 16) & 1u);
  return (unsigned short)(r >> 16);
}
__device__ inline float bf2f(unsigned int b) {
  return __uint_as_float(b << 16);
}

// ---------------------------------------------------------------------------
// split body: fp32 [R][K] -> hi/lo bf16 in MFMA-fragment-major layout.
// ---------------------------------------------------------------------------
__device__ inline void split_body(const float* __restrict__ in,
                                  unsigned short* __restrict__ hi,
                                  unsigned short* __restrict__ lo,
                                  int R, int K8, int idx) {
  int r = idx & 15;
  int t = idx >> 4;
  int kq = t % K8;
  int rb = t / K8;
  int row = rb * 16 + r;
  float v[8] = {0.f, 0.f, 0.f, 0.f, 0.f, 0.f, 0.f, 0.f};
  if (row < R) {
    const float* p = in + (size_t)row * (K8 * 8) + kq * 8;
    float4 a = *(const float4*)p;
    float4 b = *(const float4*)(p + 4);
    v[0] = a.x; v[1] = a.y; v[2] = a.z; v[3] = a.w;
    v[4] = b.x; v[5] = b.y; v[6] = b.z; v[7] = b.w;
  }
  union { unsigned short u[8]; int4 v4; } H, L;
  #pragma unroll
  for (int e = 0; e < 8; ++e) {
    unsigned short hb_ = f2bf_rne(v[e]);
    H.u[e] = hb_;
    L.u[e] = f2bf_rne(v[e] - bf2f(hb_));
  }
  *(int4*)&hi[(size_t)idx * 8] = H.v4;
  *(int4*)&lo[(size_t)idx * 8] = L.v4;
}

// Combined A split + W split + CSR degree count in ONE dispatch.
__global__ __launch_bounds__(256)
void split_frag2(const float* __restrict__ in1, unsigned short* __restrict__ hi1,
                 unsigned short* __restrict__ lo1, int R1, int K81, int total1,
                 int nb1,
                 const float* __restrict__ in2, unsigned short* __restrict__ hi2,
                 unsigned short* __restrict__ lo2, int R2, int K82, int total2,
                 int nb2,
                 const int* __restrict__ edst, int* __restrict__ deg, int E) {
  if ((int)blockIdx.x < nb1) {
    int idx = blockIdx.x * 256 + threadIdx.x;
    if (idx < total1) split_body(in1, hi1, lo1, R1, K81, idx);
  } else if ((int)blockIdx.x < nb1 + nb2) {
    int idx = (blockIdx.x - nb1) * 256 + threadIdx.x;
    if (idx < total2) split_body(in2, hi2, lo2, R2, K82, idx);
  } else {
    int e = (blockIdx.x - nb1 - nb2) * 256 + threadIdx.x;
    if (e < E) atomicAdd(&deg[edst[e]], 1);
  }
}

// ---------------------------------------------------------------------------
// LDS-free split-bf16 MFMA GEMM (R8 config — best measured: ~45us, MfmaUtil
// 28%). NOTE (R11): smaller tiles raise occupancy but halve per-wave
// arithmetic intensity -> 2x slower. NOTE (R10): register double-buffer is
// neutral. Grid-limited to ~3 blocks/CU; split-K doesn't pay. Frozen.
// si/sj now HEAD-MAJOR [head][n] (XCD L2 affinity for agg's gathers).
// ---------------------------------------------------------------------------
__global__ __launch_bounds__(128, 3)
void gemm_frag(const unsigned short* __restrict__ Afh,
               const unsigned short* __restrict__ Afl,
               const unsigned short* __restrict__ Bfh,
               const unsigned short* __restrict__ Bfl,
               const float* __restrict__ avec,
               unsigned short* __restrict__ hb,
               float* __restrict__ si, float* __restrict__ sj,
               int M, int K) {
  __shared__ float rsi[64][2];
  __shared__ float rsj[64][2];
  int tid = threadIdx.x;
  int wave = tid >> 6, lane = tid & 63;
  int r = lane & 15, q = lane >> 4;

  int blk = blockIdx.x;
  int rr = blk & 7, gg = blk >> 3;
  int head = gg & 7;
  int mtile = (gg >> 3) * 8 + rr;     // blk%8 == mtile%8 -> XCD affinity
  int m0 = mtile * 64;
  int wn = wave * 64;
  int K8 = K >> 3;

  const bf16x8* pAh = (const bf16x8*)Afh;
  const bf16x8* pAl = (const bf16x8*)Afl;
  const bf16x8* pBh = (const bf16x8*)Bfh;
  const bf16x8* pBl = (const bf16x8*)Bfl;
  size_t rstep = (size_t)K8 * 16;
  size_t aidx = (size_t)(m0 >> 4) * rstep + (size_t)q * 16 + r;
  size_t bidx = (size_t)(head * 8 + (wn >> 4)) * rstep + (size_t)q * 16 + r;

  f32x4 acc[4][4] = {};

  for (int k0 = 0; k0 < K; k0 += 32, aidx += 64, bidx += 64) {
    bf16x8 ah[4], al[4], bh[4], bl[4];
    #pragma unroll
    for (int i = 0; i < 4; ++i) {
      ah[i] = pAh[aidx + i * rstep];
      al[i] = pAl[aidx + i * rstep];
      bh[i] = pBh[bidx + i * rstep];
      bl[i] = pBl[bidx + i * rstep];
    }
    #pragma unroll
    for (int i = 0; i < 4; ++i)
      #pragma unroll
      for (int j = 0; j < 4; ++j) {
        acc[i][j] = __builtin_amdgcn_mfma_f32_16x16x32_bf16(ah[i], bh[j], acc[i][j], 0, 0, 0);
        acc[i][j] = __builtin_amdgcn_mfma_f32_16x16x32_bf16(ah[i], bl[j], acc[i][j], 0, 0, 0);
        acc[i][j] = __builtin_amdgcn_mfma_f32_16x16x32_bf16(al[i], bh[j], acc[i][j], 0, 0, 0);
      }
  }

  // --- epilogue: C/D layout col = r, row = q*4 + reg (per 16x16 frag) ---
  const float* av = avec + (size_t)head * (2 * HID);
  float aiv[4], ajv[4];
  #pragma unroll
  for (int j = 0; j < 4; ++j) {
    int c = wn + j * 16 + r;
    aiv[j] = av[c];
    ajv[j] = av[HID + c];
  }
  #pragma unroll
  for (int i = 0; i < 4; ++i) {
    #pragma unroll
    for (int reg = 0; reg < 4; ++reg) {
      int lrow = i * 16 + q * 4 + reg;
      int row = m0 + lrow;
      float vsi = 0.f, vsj = 0.f;
      #pragma unroll
      for (int j = 0; j < 4; ++j) {
        float v = acc[i][j][reg];
        vsi = fmaf(v, aiv[j], vsi);
        vsj = fmaf(v, ajv[j], vsj);
        if (row < M)
          hb[((size_t)head * M + row) * HID + wn + j * 16 + r] = f2bf_rne(v);
      }
      #pragma unroll
      for (int o = 8; o >= 1; o >>= 1) {
        vsi += __shfl_xor(vsi, o);
        vsj += __shfl_xor(vsj, o);
      }
      if (r == 0) {
        rsi[lrow][wave] = vsi;
        rsj[lrow][wave] = vsj;
      }
    }
  }
  __syncthreads();
  if (tid < 64) {
    int row = m0 + tid;
    if (row < M) {
      si[(size_t)head * M + row] = rsi[tid][0] + rsi[tid][1];
      sj[(size_t)head * M + row] = rsj[tid][0] + rsj[tid][1];
    }
  }
}

// ---------------------------------------------------------------------------
// CSR build (count fused into split_frag2)
// ---------------------------------------------------------------------------
__global__ __launch_bounds__(1024)
void scan_kernel(const int* __restrict__ deg, int* __restrict__ off, int N) {
  __shared__ int sums[1024];
  const int PER = 10;
  int tid = threadIdx.x;
  int base = tid * PER;
  int loc[PER];
  int run = 0;
  #pragma unroll
  for (int j = 0; j < PER; ++j) {
    int v = (base + j < N) ? deg[base + j] : 0;
    run += v;
    loc[j] = run;
  }
  sums[tid] = run;
  __syncthreads();
  for (int o = 1; o < 1024; o <<= 1) {
    int v = (tid >= o) ? sums[tid - o] : 0;
    __syncthreads();
    sums[tid] += v;
    __syncthreads();
  }
  int ex = sums[tid] - run;
  if (tid == 0) off[0] = 0;
  #pragma unroll
  for (int j = 0; j < PER; ++j)
    if (base + j < N) off[base + j + 1] = ex + loc[j];
}

__global__ void fill_kernel(const int* __restrict__ src, const int* __restrict__ dst,
                            const int* __restrict__ off, int* __restrict__ cursor,
                            int* __restrict__ ssrc, int E) {
  int e = blockIdx.x * blockDim.x + threadIdx.x;
  if (e < E) {
    int d = dst[e];
    int p = atomicAdd(&cursor[d], 1);
    ssrc[off[d] + p] = src[e];
  }
}

// ---------------------------------------------------------------------------
// FUSED softmax + aggregation: one wave per (dst, head); head=blk&7.
// si/sj head-major (XCD-local gathers). __expf fast exp (args <= 0).
// Gather loop: per-wave LDS (src,w) table + v_pk_fma_f32 accumulate.
// ---------------------------------------------------------------------------
__global__ __launch_bounds__(512)
void gat_aggregate7(const unsigned short* __restrict__ hb,
                    const float* __restrict__ si, const float* __restrict__ sj,
                    const int* __restrict__ off, const int* __restrict__ ssrc,
                    unsigned short* __restrict__ aggb, int N) {
  __shared__ int2 prs[8][64];   // per-wave (src, w) table
  int head = blockIdx.x & 7;
  int wv = threadIdx.x >> 6;
  int n = (blockIdx.x >> 3) * 8 + wv;   // grid == N/8 blocks: n < N always
  int lane = threadIdx.x & 63;
  int grp = lane >> 4;
  int l = lane & 15;
  const unsigned short* hbase = hb + (size_t)head * N * HID;
  const float* sjh = sj + (size_t)head * N;
  int begin = off[n], end = off[n + 1];
  int deg = end - begin;
  int dmin = deg < 64 ? deg : 64;
  float s_i = si[(size_t)head * N + n];

  // --- phase 1: per-lane edge score ---
  int src0 = 0;
  float sc0 = -INFINITY;
  if (lane < deg) {
    src0 = ssrc[begin + lane];
    float t = s_i + sjh[src0];
    sc0 = t > 0.f ? t : 0.01f * t;
  }
  float m = sc0;
  for (int e2 = 64 + lane; e2 < deg; e2 += 64) {     // rare tail max
    int s = ssrc[begin + e2];
    float t = s_i + sjh[s];
    t = t > 0.f ? t : 0.01f * t;
    m = fmaxf(m, t);
  }
  #pragma unroll
  for (int o = 1; o <= 32; o <<= 1) m = fmaxf(m, __shfl_xor(m, o));

  float w0 = (lane < deg) ? __expf(sc0 - m) : 0.f;
  float den = w0;
  for (int e2 = 64 + lane; e2 < deg; e2 += 64) {     // rare tail denom
    int s = ssrc[begin + e2];
    float t = s_i + sjh[s];
    t = t > 0.f ? t : 0.01f * t;
    den += __expf(t - m);
  }
  #pragma unroll
  for (int o = 1; o <= 32; o <<= 1) den += __shfl_xor(den, o);

  // stage pairs (w=0 for lanes >= deg; src=0 -> safe dummy gather)
  prs[wv][lane] = make_int2(src0, __float_as_int(w0));
  // wave-synchronous LDS: ensure writes land + block compiler reorder.
  __asm__ volatile("s_waitcnt lgkmcnt(0)" ::: "memory");

  // --- gather phase: 4 groups x 16 lanes, 16 edges per iteration ---
  v2f a01 = {0.f, 0.f}, a23 = {0.f, 0.f}, a45 = {0.f, 0.f}, a67 = {0.f, 0.f};

  for (int e0 = 0; e0 < dmin; e0 += 16) {
    float we[4];
    int se[4];
    #pragma unroll
    for (int u = 0; u < 4; ++u) {
      int e = e0 + u * 4 + grp;       // e <= 63 always (e0 <= 48)
      int2 p = prs[wv][e];
      se[u] = p.x;
      we[u] = __int_as_float(p.y);    // already 0 beyond deg
    }
    int4 pv[4];
    #pragma unroll
    for (int u = 0; u < 4; ++u)
      pv[u] = *(const int4*)&hbase[(size_t)se[u] * HID + l * 8];
    #pragma unroll
    for (int u = 0; u < 4; ++u) {
      v2f w2 = {we[u], we[u]};
      int4 p = pv[u];
      v2f t0 = {bf2f((unsigned)p.x & 0xffffu), __uint_as_float((unsigned)p.x & 0xffff0000u)};
      v2f t1 = {bf2f((unsigned)p.y & 0xffffu), __uint_as_float((unsigned)p.y & 0xffff0000u)};
      v2f t2 = {bf2f((unsigned)p.z & 0xffffu), __uint_as_float((unsigned)p.z & 0xffff0000u)};
      v2f t3 = {bf2f((unsigned)p.w & 0xffffu), __uint_as_float((unsigned)p.w & 0xffff0000u)};
      a01 += w2 * t0;                 // v_pk_fma_f32
      a23 += w2 * t1;
      a45 += w2 * t2;
      a67 += w2 * t3;
    }
  }
  // rare tail: deg > 64, recompute weights per group
  for (int e2 = 64; e2 < deg; e2 += 4) {
    int e = e2 + grp;
    bool valid = e < deg;
    int s = ssrc[valid ? begin + e : begin];
    float t = s_i + sjh[s];
    t = t > 0.f ? t : 0.01f * t;
    float wu = valid ? __expf(t - m) : 0.f;
    v2f w2 = {wu, wu};
    int4 p = *(const int4*)&hbase[(size_t)s * HID + l * 8];
    v2f t0 = {bf2f((unsigned)p.x & 0xffffu), __uint_as_float((unsigned)p.x & 0xffff0000u)};
    v2f t1 = {bf2f((unsigned)p.y & 0xffffu), __uint_as_float((unsigned)p.y & 0xffff0000u)};
    v2f t2 = {bf2f((unsigned)p.z & 0xffffu), __uint_as_float((unsigned)p.z & 0xffff0000u)};
    v2f t3 = {bf2f((unsigned)p.w & 0xffffu), __uint_as_float((unsigned)p.w & 0xffff0000u)};
    a01 += w2 * t0; a23 += w2 * t1; a45 += w2 * t2; a67 += w2 * t3;
  }

  // reduce across the 4 edge groups
  #pragma unroll
  for (int o = 16; o <= 32; o <<= 1) {
    a01.x += __shfl_xor(a01.x, o); a01.y += __shfl_xor(a01.y, o);
    a23.x += __shfl_xor(a23.x, o); a23.y += __shfl_xor(a23.y, o);
    a45.x += __shfl_xor(a45.x, o); a45.y += __shfl_xor(a45.y, o);
    a67.x += __shfl_xor(a67.x, o); a67.y += __shfl_xor(a67.y, o);
  }

  if (grp == 0) {
    float inv = den > 0.f ? 1.0f / den : 0.f;
    union { unsigned short u[8]; int4 v4; } P;
    P.u[0] = f2bf_rne(a01.x * inv); P.u[1] = f2bf_rne(a01.y * inv);
    P.u[2] = f2bf_rne(a23.x * inv); P.u[3] = f2bf_rne(a23.y * inv);
    P.u[4] = f2bf_rne(a45.x * inv); P.u[5] = f2bf_rne(a45.y * inv);
    P.u[6] = f2bf_rne(a67.x * inv); P.u[7] = f2bf_rne(a67.y * inv);
    *(int4*)&aggb[((size_t)head * N + n) * HID + l * 8] = P.v4;
  }
}

// ---------------------------------------------------------------------------
// Head mean + ELU (bf16 aggbuf), writing layer-2 A in frag-major split form,
// FUSED with the W2 split (blocks >= nbHM).
// ---------------------------------------------------------------------------
__global__ __launch_bounds__(256)
void headmean_frag_w2(const unsigned short* __restrict__ aggb,
                      unsigned short* __restrict__ hiA, unsigned short* __restrict__ loA,
                      int N, int nbHM,
                      const float* __restrict__ W2, unsigned short* __restrict__ hiB,
                      unsigned short* __restrict__ loB, int totalB) {
  if ((int)blockIdx.x >= nbHM) {
    int idx = (blockIdx.x - nbHM) * 256 + threadIdx.x;
    if (idx < totalB) split_body(W2, hiB, loB, HEADS * HID, 16, idx);
    return;
  }
  int idx = blockIdx.x * 256 + threadIdx.x;   // (rb,kq,r), K8=16
  int total = ((N + 15) / 16) * 256;
  if (idx >= total) return;
  int r = idx & 15;
  int kq = (idx >> 4) & 15;
  int rb = idx >> 8;
  int n = rb * 16 + r;
  float s[8] = {0.f, 0.f, 0.f, 0.f, 0.f, 0.f, 0.f, 0.f};
  if (n < N) {
    #pragma unroll
    for (int hh = 0; hh < HEADS; ++hh) {
      int4 pv = *(const int4*)&aggb[((size_t)hh * N + n) * HID + kq * 8];
      s[0] += bf2f((unsigned)pv.x & 0xffffu);
      s[1] += __uint_as_float((unsigned)pv.x & 0xffff0000u);
      s[2] += bf2f((unsigned)pv.y & 0xffffu);
      s[3] += __uint_as_float((unsigned)pv.y & 0xffff0000u);
      s[4] += bf2f((unsigned)pv.z & 0xffffu);
      s[5] += __uint_as_float((unsigned)pv.z & 0xffff0000u);
      s[6] += bf2f((unsigned)pv.w & 0xffffu);
      s[7] += __uint_as_float((unsigned)pv.w & 0xffff0000u);
    }
  }
  union { unsigned short u[8]; int4 v4; } H, L;
  #pragma unroll
  for (int e = 0; e < 8; ++e) {
    float v = s[e] * (1.0f / HEADS);
    v = v > 0.f ? v : (__expf(v) - 1.0f);   // ELU
    unsigned short hb_ = f2bf_rne(v);
    H.u[e] = hb_;
    L.u[e] = f2bf_rne(v - bf2f(hb_));
  }
  *(int4*)&hiA[(size_t)idx * 8] = H.v4;
  *(int4*)&loA[(size_t)idx * 8] = L.v4;
}

// ---------------------------------------------------------------------------
// Layer-2 tail: head mean + ELU + graph pooling fused (no emb2 materialized).
// ---------------------------------------------------------------------------
__global__ __launch_bounds__(256)
void headmean_pool(const unsigned short* __restrict__ aggb, float* __restrict__ g,
                   int N) {
  __shared__ float sm[16][128];
  int t = threadIdx.x;
  int nl = t >> 4, dg = t & 15;
  int n = blockIdx.x * 16 + nl;
  float v[8] = {0.f, 0.f, 0.f, 0.f, 0.f, 0.f, 0.f, 0.f};
  if (n < N) {
    #pragma unroll
    for (int hh = 0; hh < HEADS; ++hh) {
      int4 pv = *(const int4*)&aggb[((size_t)hh * N + n) * HID + dg * 8];
      v[0] += bf2f((unsigned)pv.x & 0xffffu);
      v[1] += __uint_as_float((unsigned)pv.x & 0xffff0000u);
      v[2] += bf2f((unsigned)pv.y & 0xffffu);
      v[3] += __uint_as_float((unsigned)pv.y & 0xffff0000u);
      v[4] += bf2f((unsigned)pv.z & 0xffffu);
      v[5] += __uint_as_float((unsigned)pv.z & 0xffff0000u);
      v[6] += bf2f((unsigned)pv.w & 0xffffu);
      v[7] += __uint_as_float((unsigned)pv.w & 0xffff0000u);
    }
    #pragma unroll
    for (int e = 0; e < 8; ++e) {
      float x = v[e] * (1.0f / HEADS);
      v[e] = x > 0.f ? x : (__expf(x) - 1.0f);   // ELU
    }
  }
  #pragma unroll
  for (int e = 0; e < 8; ++e) sm[nl][dg * 8 + e] = v[e];
  __syncthreads();
  if (t < 128) {
    float s = 0.f;
    #pragma unroll
    for (int nn = 0; nn < 16; ++nn) s += sm[nn][t];
    atomicAdd(&g[t], s);
  }
}

// ---------------------------------------------------------------------------
// LayerNorm + MLP head
// ---------------------------------------------------------------------------
__global__ __launch_bounds__(128)
void mlp_kernel(const float* __restrict__ g, const float* __restrict__ ln_g,
                const float* __restrict__ ln_b, const float* __restrict__ Wl1,
                const float* __restrict__ bl1, const float* __restrict__ Wl2,
                const float* __restrict__ bl2, const float* __restrict__ Wl3,
                const float* __restrict__ bl3, float* __restrict__ out, float invN) {
  __shared__ float red[128];
  __shared__ float gn[128];
  __shared__ float x1[64];
  __shared__ float x2[16];
  int t = threadIdx.x;
  float gg = g[t] * invN;
  red[t] = gg;
  __syncthreads();
  for (int o = 64; o > 0; o >>= 1) {
    if (t < o) red[t] += red[t + o];
    __syncthreads();
  }
  float mu = red[0] * (1.0f / HID);
  __syncthreads();
  float dv = gg - mu;
  red[t] = dv * dv;
  __syncthreads();
  for (int o = 64; o > 0; o >>= 1) {
    if (t < o) red[t] += red[t + o];
    __syncthreads();
  }
  float var = red[0] * (1.0f / HID);
  gn[t] = dv / sqrtf(var + 1e-5f) * ln_g[t] + ln_b[t];
  __syncthreads();
  if (t < 64) {
    float s = bl1[t];
    for (int k = 0; k < 128; ++k) s += Wl1[t * 128 + k] * gn[k];
    x1[t] = s > 0.f ? s : 0.01f * s;
  }
  __syncthreads();
  if (t < 16) {
    float s = bl2[t];
    for (int k = 0; k < 64; ++k) s += Wl2[t * 64 + k] * x1[k];
    x2[t] = s > 0.f ? s : 0.01f * s;
  }
  __syncthreads();
  if (t < 16) {
    float s = bl3[t];
    for (int k = 0; k < 16; ++k) s += Wl3[t * 16 + k] * x2[k];
    out[t] = s > 0.f ? s : 0.f;
  }
}

// ---------------------------------------------------------------------------
extern "C" void kernel_launch(void* const* d_in, const int* in_sizes, int n_in,
                              void* d_out, int out_size, void* d_ws, size_t ws_size,
                              hipStream_t stream) {
  const float* x    = (const float*)d_in[0];
  const int*   esrc = (const int*)d_in[1];
  const int*   edst = (const int*)d_in[2];
  const float* W1   = (const float*)d_in[3];
  const float* a1   = (const float*)d_in[4];
  const float* W2   = (const float*)d_in[5];
  const float* a2   = (const float*)d_in[6];
  const float* ln_g = (const float*)d_in[7];
  const float* ln_b = (const float*)d_in[8];
  const float* Wl1  = (const float*)d_in[9];
  const float* bl1  = (const float*)d_in[10];
  const float* Wl2  = (const float*)d_in[11];
  const float* bl2  = (const float*)d_in[12];
  const float* Wl3  = (const float*)d_in[13];
  const float* bl3  = (const float*)d_in[14];
  float* out = (float*)d_out;

  const int RBPAD = 640;  // row-blocks padded (10240 rows) for in-bounds frags

  // workspace carve-up (g, deg, cur contiguous -> one memset)
  unsigned short* aggb = (unsigned short*)d_ws;                 // 20.5 MB
  float* si   = (float*)(aggb + (size_t)N_NODES * HEADS * HID); // 80,000
  float* sj   = si + N_NODES * HEADS;                           // 80,000
  float* g    = sj + N_NODES * HEADS;                           // 128
  int*   deg  = (int*)(g + 128);                                // 10,000
  int*   cur  = deg + N_NODES;                                  // 10,000
  int*   off  = cur + N_NODES;                                  // 10,001 -> pad 10,004
  int*   ssrc = off + 10004;                                    // 160,000
  unsigned short* Afh = (unsigned short*)(ssrc + N_EDGES);      // 640*64*128 us
  unsigned short* Afl = Afh + (size_t)RBPAD * 64 * 128;
  unsigned short* Bfh = Afl + (size_t)RBPAD * 64 * 128;
  unsigned short* Bfl = Bfh + (size_t)64 * 64 * 128;
  unsigned short* hb  = Bfl + (size_t)64 * 64 * 128;            // 20.5 MB

  // zero g + deg + cur in ONE memset (contiguous)
  hipMemsetAsync(g, 0, 128 * sizeof(float) + 2 * N_NODES * sizeof(int), stream);

  int gemmGrid = 160 * HEADS;                 // 1280 blocks of 128 threads
  int aggGrid = (N_NODES / 8) * 8;            // 10000 blocks (N % 8 == 0)

  // ---- Layer 1: fused A-split + W1-split + CSR count in one dispatch ----
  {
    int totalA = RBPAD * 64 * 16;             // K8=64
    int nbA = (totalA + 255) / 256;           // 2560
    int totalB = 64 * 64 * 16;                // 1024 rows, K8=64
    int nbB = (totalB + 255) / 256;           // 256
    int nbE = (N_EDGES + 255) / 256;          // 625
    split_frag2<<<nbA + nbB + nbE, 256, 0, stream>>>(
        x, Afh, Afl, N_NODES, 64, totalA, nbA,
        W1, Bfh, Bfl, HEADS * HID, 64, totalB, nbB,
        edst, deg, N_EDGES);
  }
  scan_kernel<<<1, 1024, 0, stream>>>(deg, off, N_NODES);
  fill_kernel<<<(N_EDGES + 255) / 256, 256, 0, stream>>>(esrc, edst, off, cur, ssrc, N_EDGES);

  gemm_frag<<<gemmGrid, 128, 0, stream>>>(Afh, Afl, Bfh, Bfl, a1, hb,
                                          si, sj, N_NODES, N_FEAT);
  gat_aggregate7<<<aggGrid, 512, 0, stream>>>(hb, si, sj, off, ssrc, aggb, N_NODES);
  {
    int nbHM = ((N_NODES + 15) / 16 * 256 + 255) / 256;   // 625
    int totalB = 64 * 16 * 16;                            // W2: 1024 rows, K8=16
    int nbB = (totalB + 255) / 256;                       // 64
    headmean_frag_w2<<<nbHM + nbB, 256, 0, stream>>>(aggb, Afh, Afl, N_NODES, nbHM,
                                                     W2, Bfh, Bfl, totalB);
  }

  // ---- Layer 2 ----
  gemm_frag<<<gemmGrid, 128, 0, stream>>>(Afh, Afl, Bfh, Bfl, a2, hb,
                                          si, sj, N_NODES, HID);
  gat_aggregate7<<<aggGrid, 512, 0, stream>>>(hb, si, sj, off, ssrc, aggb, N_NODES);

  // ---- fused head-mean + pooling + MLP head ----
  headmean_pool<<<(N_NODES + 15) / 16, 256, 0, stream>>>(aggb, g, N_NODES);
  mlp_kernel<<<1, 128, 0, stream>>>(g, ln_g, ln_b, Wl1, bl1, Wl2, bl2, Wl3, bl3,
                                    out, 1.0f / N_NODES);
}